// Round 2
// baseline (860.858 us; speedup 1.0000x reference)
//
#include <hip/hip_runtime.h>
#include <cstdint>
#include <cstddef>

// Problem constants (fixed by the reference).
#define NUM_AUDIOS 64
#define NODES_PER  800
#define NN         51200
#define EE         409600
// IN_C=512, HID=256, OUT=256, HEADS=2 -> both GAT linears output [N, 512] (2 heads x 256)

typedef __attribute__((ext_vector_type(8))) unsigned short ushort8;
typedef __attribute__((ext_vector_type(4))) unsigned short ushort4v;
typedef __attribute__((ext_vector_type(8))) __bf16 bf16x8;
typedef __attribute__((ext_vector_type(4))) float f32x4;

__device__ __forceinline__ float b2f(unsigned short h) {
  return __uint_as_float(((unsigned)h) << 16);
}
__device__ __forceinline__ unsigned short f2b(float f) {
  unsigned u = __float_as_uint(f);
  u += 0x7fffu + ((u >> 16) & 1u);  // RNE
  return (unsigned short)(u >> 16);
}
__device__ __forceinline__ float lrelu(float v) { return v > 0.f ? v : 0.2f * v; }

// Canonical bf16 parameter block offsets (u16 units)
#define P_AS1 0
#define P_AD1 512
#define P_B1  1024
#define P_AS2 1536
#define P_AD2 2048
#define P_B2  2560
#define P_WATT 3072
#define P_BATT 3328
#define P_WCLS 3336
#define P_BCLS 3848

// Zero region: counts|cursor|attended|al_s1|al_d1|al_s2|al_d2 (contiguous, 2113536 B)
#define ZERO_F4 132096   // float4 count
#define ZERO_BLOCKS 516  // 516*256 = 132096

// ---------------- prolog: zero atomic buffers + dtype probe ----------------
__global__ __launch_bounds__(256) void prolog0_k(float4* __restrict__ zbase,
                                                 const unsigned short* __restrict__ x,
                                                 int* __restrict__ flag) {
  const int i = blockIdx.x * 256 + threadIdx.x;
  if (i < ZERO_F4) zbase[i] = (float4){0.f, 0.f, 0.f, 0.f};
  if (blockIdx.x == 0) {
    __shared__ int s;
    if (threadIdx.x == 0) s = 0;
    __syncthreads();
    int big = 0;
    for (int k = threadIdx.x; k < 4096; k += 256) {
      const float v = b2f(x[k]);
      if (!(__builtin_fabsf(v) <= 1e4f)) big = 1;  // catches >1e4, inf, NaN
    }
    if (big) atomicOr(&s, 1);
    __syncthreads();
    if (threadIdx.x == 0) *flag = s;  // 1 = fp32 inputs, 0 = bf16 inputs
  }
}

// ---------------- union prep: params | transpose W1 | transpose W2 | hist ------
#define PB_PAR  10
#define PB_T1   (PB_PAR + 1024)
#define PB_T2   (PB_T1 + 512)
#define PB_HIST (PB_T2 + 1600)   // total grid = 3146

__global__ __launch_bounds__(256) void prep_k(
    const void* __restrict__ W1, unsigned short* __restrict__ W1T,
    const void* __restrict__ W2, unsigned short* __restrict__ W2T,
    const void* p0, const void* p1, const void* p2, const void* p3, const void* p4,
    const void* p5, const void* p6, const void* p7, const void* p8, const void* p9,
    unsigned short* __restrict__ params,
    const int* __restrict__ dst, int* __restrict__ counts,
    const int* __restrict__ flagp) {
  const int b = blockIdx.x, tid = threadIdx.x;
  const int f = *flagp;
  if (b < PB_PAR) {                        // small params -> canonical bf16 block
    const void* srcs[10] = {p0, p1, p2, p3, p4, p5, p6, p7, p8, p9};
    const int offs[10] = {P_AS1, P_AD1, P_B1, P_AS2, P_AD2, P_B2, P_WATT, P_BATT, P_WCLS, P_BCLS};
    const int lens[10] = {512, 512, 256, 512, 512, 256, 256, 1, 512, 2};
    const int s = b;
    for (int i = tid; i < lens[s]; i += 256)
      params[offs[s] + i] = f ? f2b(((const float*)srcs[s])[i])
                              : ((const unsigned short*)srcs[s])[i];
  } else if (b < PB_T1) {                  // W1 [512,512] -> W1T
    const int idx = (b - PB_PAR) * 256 + tid;
    const int n = idx >> 9, k = idx & 511;
    W1T[idx] = f ? f2b(((const float*)W1)[(size_t)k * 512 + n])
                 : ((const unsigned short*)W1)[(size_t)k * 512 + n];
  } else if (b < PB_T2) {                  // W2 [256,512] -> W2T
    const int idx = (b - PB_T1) * 256 + tid;
    const int n = idx >> 8, k = idx & 255;
    W2T[idx] = f ? f2b(((const float*)W2)[(size_t)k * 512 + n])
                 : ((const unsigned short*)W2)[(size_t)k * 512 + n];
  } else {                                 // histogram of dst
    const int e = (b - PB_T2) * 256 + tid;
    atomicAdd(&counts[dst[e]], 1);
  }
}

// ---------------- CSR build ----------------
__global__ __launch_bounds__(256) void rowptr_k(const int* __restrict__ counts, int* __restrict__ row_ptr) {
  __shared__ int sh[800];
  __shared__ int pre[200];
  const int a = blockIdx.x, t = threadIdx.x;
  for (int i = t; i < 800; i += 256) sh[i] = counts[a * 800 + i];
  __syncthreads();
  if (t < 200) pre[t] = sh[t * 4] + sh[t * 4 + 1] + sh[t * 4 + 2] + sh[t * 4 + 3];
  __syncthreads();
  if (t == 0) {
    int run = 0;
    for (int i = 0; i < 200; ++i) { const int v = pre[i]; pre[i] = run; run += v; }
  }
  __syncthreads();
  if (t < 200) {
    int b = a * 6400 + pre[t];
#pragma unroll
    for (int j = 0; j < 4; ++j) { row_ptr[a * 800 + t * 4 + j] = b; b += sh[t * 4 + j]; }
  }
}

__global__ __launch_bounds__(256) void scatter_k(const int* __restrict__ src, const int* __restrict__ dst,
                                                 const int* __restrict__ row_ptr, int* __restrict__ cursor,
                                                 int* __restrict__ ssrc) {
  const int e = blockIdx.x * 256 + threadIdx.x;
  const int d = dst[e];
  const int p = atomicAdd(&cursor[d], 1);
  ssrc[row_ptr[d] + p] = src[e];
}

// ---------------- GEMM core fragment+MFMA step (XOR bank-deswizzle on read) ----
__device__ __forceinline__ void mfma_tile(const unsigned short* As, const unsigned short* Bs,
                                          int wm, int wn, int row, int quad, f32x4 acc[4][4]) {
  bf16x8 af[4], bq[4];
  const int pa = (quad ^ (row & 3)) * 8;  // physical k-chunk (bank swizzle)
#pragma unroll
  for (int i = 0; i < 4; ++i) {
    af[i] = *(const bf16x8*)&As[(wm * 64 + i * 16 + row) * 32 + pa];
    bq[i] = *(const bf16x8*)&Bs[(wn * 64 + i * 16 + row) * 32 + pa];
  }
#pragma unroll
  for (int i = 0; i < 4; ++i)
#pragma unroll
    for (int j = 0; j < 4; ++j)
      acc[i][j] = __builtin_amdgcn_mfma_f32_16x16x32_bf16(af[i], bq[j], acc[i][j], 0, 0, 0);
}

// ---------------- GEMM + fused attention-logit partials ----------------
// C[M,512] = A[M,K] @ B (BT[512,K]). 128x128 tile, mfma 16x16x32 bf16.
// A dtype: bf16 (aflag null or *aflag==0, async DMA staging) or fp32
// (*aflag==1: VGPR load + convert + ds_write). XCD-swizzled 1D grid:
// g=id&7 -> XCD; row-blocks partitioned per XCD, columns innermost (A L2 reuse).
// LDS layout XOR-swizzled: logical k-chunk q of row r at physical q^(r&3).
// Epilogue: C tile staged via LDS (32KB) -> coalesced 16B stores.
// quad-rotated j-chunk ds_writes keep 32 banks busy (2-way = free).
__global__ __launch_bounds__(256) void gemm_bt(const void* __restrict__ Araw,
                                               const unsigned short* __restrict__ BT,
                                               unsigned short* __restrict__ C,
                                               int K, int Nn,
                                               const unsigned short* __restrict__ a_s,
                                               const unsigned short* __restrict__ a_d,
                                               float* __restrict__ al_s,
                                               float* __restrict__ al_d,
                                               const int* __restrict__ aflag) {
  __shared__ unsigned short smem[16384];   // 32KB: K-loop uses [0,8192); epilogue uses all
  unsigned short* As = smem;               // 128*32 ushorts = 8KB
  unsigned short* Bs = smem + 4096;        // 8KB
  const int tid = threadIdx.x;
  const int wave = tid >> 6, lane = tid & 63;
  const int bid = blockIdx.x;
  const int g = bid & 7, bt = bid >> 3;              // 8 XCDs x 200 blocks
  const int m0 = (g * 50 + (bt >> 2)) * 128;         // 50 row-blocks per XCD
  const int n0 = (bt & 3) * 128;                     // columns innermost
  const int wm = wave >> 1, wn = wave & 1;
  const int row = lane & 15, quad = lane >> 4;
  f32x4 acc[4][4];
#pragma unroll
  for (int i = 0; i < 4; ++i)
#pragma unroll
    for (int j = 0; j < 4; ++j) acc[i][j] = (f32x4){0.f, 0.f, 0.f, 0.f};

  const bool a_is_f32 = (aflag != nullptr) && (*aflag != 0);
  const unsigned short* A16 = (const unsigned short*)Araw;
  const float* A32 = (const float*)Araw;
  // staging index: chunk cc = r*256+tid; row = cc>>2; physical k-slot = cc&3;
  // global (logical) k-chunk = (cc&3) ^ (row&3)
  const int srow0 = tid >> 2;                        // r=0 row; r=1 row = +64
  const int kph = tid & 3;

  if (!a_is_f32) {
    for (int k0 = 0; k0 < K; k0 += 32) {
      __syncthreads();  // previous iteration's LDS readers done
#pragma unroll
      for (int r = 0; r < 2; ++r) {
        const int arow = r * 64 + srow0;
        const int kc = ((kph ^ (arow & 3)) * 8);
        __builtin_amdgcn_global_load_lds(
            (const __attribute__((address_space(1))) void*)(A16 + (size_t)(m0 + arow) * K + k0 + kc),
            (__attribute__((address_space(3))) void*)(As + (size_t)(r * 256 + wave * 64) * 8),
            16, 0, 0);
        __builtin_amdgcn_global_load_lds(
            (const __attribute__((address_space(1))) void*)(BT + (size_t)(n0 + arow) * K + k0 + kc),
            (__attribute__((address_space(3))) void*)(Bs + (size_t)(r * 256 + wave * 64) * 8),
            16, 0, 0);
      }
      __syncthreads();  // vmcnt(0) drain before barrier -> DMA landed
      mfma_tile(As, Bs, wm, wn, row, quad, acc);
    }
  } else {
    for (int k0 = 0; k0 < K; k0 += 32) {
      ushort8 pk[2];
#pragma unroll
      for (int r = 0; r < 2; ++r) {
        const int arow = r * 64 + srow0;
        const int kc = ((kph ^ (arow & 3)) * 8);
        const float* p = A32 + (size_t)(m0 + arow) * K + k0 + kc;
        const float4 f0 = *(const float4*)p;
        const float4 f1 = *(const float4*)(p + 4);
        pk[r][0] = f2b(f0.x); pk[r][1] = f2b(f0.y); pk[r][2] = f2b(f0.z); pk[r][3] = f2b(f0.w);
        pk[r][4] = f2b(f1.x); pk[r][5] = f2b(f1.y); pk[r][6] = f2b(f1.z); pk[r][7] = f2b(f1.w);
      }
      __syncthreads();  // previous iteration's LDS readers done
#pragma unroll
      for (int r = 0; r < 2; ++r) {
        const int arow = r * 64 + srow0;
        const int kc = ((kph ^ (arow & 3)) * 8);
        __builtin_amdgcn_global_load_lds(
            (const __attribute__((address_space(1))) void*)(BT + (size_t)(n0 + arow) * K + k0 + kc),
            (__attribute__((address_space(3))) void*)(Bs + (size_t)(r * 256 + wave * 64) * 8),
            16, 0, 0);
        *(ushort8*)&As[(size_t)(r * 256 + tid) * 8] = pk[r];
      }
      __syncthreads();  // ds_writes visible + B DMA drained (vmcnt0 before barrier)
      mfma_tile(As, Bs, wm, wn, row, quad, acc);
    }
  }

  // ---------------- epilogue: LDS-staged coalesced C store ----------------
  // C/D layout (verified m89/m91): col = lane&15, row = quad*4 + reg
  const int col = lane & 15;
  __syncthreads();  // all mfma LDS reads done before smem is overwritten
  {
    // Each lane writes 64 bf16 values into canonical [row][col] layout.
    // j-chunk rotated by quad: the 4 quads of one instruction hit 4 distinct
    // 32B chunks -> 32 banks, 2 lanes/bank (free).
#pragma unroll
    for (int i = 0; i < 4; ++i)
#pragma unroll
      for (int jj = 0; jj < 4; ++jj) {
        const int j = (jj + quad) & 3;
#pragma unroll
        for (int r = 0; r < 4; ++r) {
          const int rl = wm * 64 + i * 16 + quad * 4 + r;
          const int cl = wn * 64 + j * 16 + col;
          smem[rl * 128 + cl] = f2b(acc[i][j][r]);
        }
      }
  }
  __syncthreads();
  {
    const int rloc = tid >> 4;           // 0..15
    const int c8 = (tid & 15) * 8;       // ushort col base, 16B aligned
#pragma unroll
    for (int s = 0; s < 8; ++s) {
      const int rl = s * 16 + rloc;
      const ushort8 v = *(const ushort8*)&smem[rl * 128 + c8];
      *(ushort8*)&C[(size_t)(m0 + rl) * Nn + n0 + c8] = v;
    }
  }

  // Fused al partials: head = gn>>8 is wave-uniform (n0+wn*64 multiple of 64).
  {
    const int head = (n0 + wn * 64) >> 8;
    float as4[4], ad4[4];
#pragma unroll
    for (int j = 0; j < 4; ++j) {
      const int gn = n0 + wn * 64 + j * 16 + col;
      as4[j] = b2f(a_s[gn]);
      ad4[j] = b2f(a_d[gn]);
    }
#pragma unroll
    for (int i = 0; i < 4; ++i)
#pragma unroll
      for (int r = 0; r < 4; ++r) {
        float ps = 0.f, pd = 0.f;
#pragma unroll
        for (int j = 0; j < 4; ++j) { ps += acc[i][j][r] * as4[j]; pd += acc[i][j][r] * ad4[j]; }
#pragma unroll
        for (int off = 1; off < 16; off <<= 1) {  // reduce the 16 lanes sharing this row
          ps += __shfl_xor(ps, off);
          pd += __shfl_xor(pd, off);
        }
        if (col == 0) {
          const int gm = m0 + wm * 64 + i * 16 + quad * 4 + r;
          atomicAdd(&al_s[gm * 2 + head], ps);
          atomicAdd(&al_d[gm * 2 + head], pd);
        }
      }
  }
}

// ---------------- GAT aggregate: one wave per node, XCD-pinned audios ----------
// Edge-parallel scoring; per-edge w,s broadcast via __shfl. lrelu monotone =>
// max e_i = lrelu(max al_s_i + ald). Optional lg: fused temporal logits.
__global__ __launch_bounds__(256) void agg_k(const unsigned short* __restrict__ h,
                                             const float* __restrict__ al_s, const float* __restrict__ al_d,
                                             const int* __restrict__ row_ptr, const int* __restrict__ counts,
                                             const int* __restrict__ ssrc, const unsigned short* __restrict__ bias,
                                             unsigned short* __restrict__ out, int do_relu,
                                             void* __restrict__ out2, const int* __restrict__ flagp,
                                             const unsigned short* __restrict__ watt,
                                             float* __restrict__ lg) {
  const int wave = threadIdx.x >> 6, lane = threadIdx.x & 63;
  const int b = blockIdx.x;
  const int g = b & 7, r = b >> 3;          // g ~ XCD id (round-robin dispatch)
  const int a = g + 8 * (r / 200);          // audio pinned to XCD g
  const int chunk = r % 200;
  const int n = a * 800 + chunk * 4 + wave;
  const int head = lane >> 5;               // lanes 0-31: head0, 32-63: head1
  const int hl = lane & 31;
  const int hsel = lane & 32;
  const int deg = counts[n];
  const int base = row_ptr[n];
  const float ald = al_d[n * 2 + head];
  const float self_e = lrelu(al_s[n * 2 + head] + ald);

  float m = -1e30f;
  for (int i = hl; i < deg; i += 32) {
    const int s = ssrc[base + i];
    m = fmaxf(m, al_s[s * 2 + head]);
  }
#pragma unroll
  for (int off = 1; off < 32; off <<= 1) m = fmaxf(m, __shfl_xor(m, off));
  const float mx = fmaxf(lrelu(m + ald), self_e);

  const float w_self = __expf(self_e - mx);
  float acc[8];
  {
    const ushort8 hv = *(const ushort8*)&h[(unsigned)(n * 512 + lane * 8)];
#pragma unroll
    for (int j = 0; j < 8; ++j) acc[j] = w_self * b2f(hv[j]);
  }
  float dpart = 0.f;
  for (int t0 = 0; t0 < deg; t0 += 32) {
    const int cnt = min(32, deg - t0);
    int s = 0; float w = 0.f;
    if (hl < cnt) {
      s = ssrc[base + t0 + hl];
      w = __expf(lrelu(al_s[s * 2 + head] + ald) - mx);
      dpart += w;
    }
    for (int i = 0; i < cnt; ++i) {
      const float wb = __shfl(w, hsel + i);
      const int sb = __shfl(s, hsel + i);
      const ushort8 hv = *(const ushort8*)&h[(unsigned)(sb * 512 + lane * 8)];
#pragma unroll
      for (int j = 0; j < 8; ++j) acc[j] += wb * b2f(hv[j]);
    }
  }
#pragma unroll
  for (int off = 1; off < 32; off <<= 1) dpart += __shfl_xor(dpart, off);
  const float inv = 1.f / (w_self + dpart);

  const int c0 = hl * 8;
  ushort8 res;
  float ov[8];
#pragma unroll
  for (int j = 0; j < 8; ++j) {
    const float mine = acc[j] * inv;
    const float other = __shfl_xor(mine, 32);  // partner lane: other head, same cols
    float o = (mine + other) * 0.5f + b2f(bias[c0 + j]);
    if (do_relu) o = fmaxf(o, 0.f);
    ov[j] = o;
    res[j] = f2b(o);
  }
  if (lane < 32) {
    *(ushort8*)&out[(unsigned)(n * 256 + c0)] = res;
    if (out2) {
      if (*flagp) {
        float4* p = (float4*)((float*)out2 + (size_t)n * 256 + c0);
        p[0] = (float4){ov[0], ov[1], ov[2], ov[3]};
        p[1] = (float4){ov[4], ov[5], ov[6], ov[7]};
      } else {
        *(ushort8*)((unsigned short*)out2 + (size_t)n * 256 + c0) = res;
      }
    }
    if (lg) {  // fused temporal logits: dot(out_row, w_att) + b_att
      const ushort8 wv = *(const ushort8*)&watt[c0];
      float d = 0.f;
#pragma unroll
      for (int j = 0; j < 8; ++j) d += ov[j] * b2f(wv[j]);
#pragma unroll
      for (int off = 1; off < 32; off <<= 1) d += __shfl_xor(d, off);
      if (hl == 0) lg[n] = d + b2f(watt[256]);  // b_att sits right after w_att
    }
  }
}

// ---------------- temporal attention, grid-parallel ----------------
__global__ __launch_bounds__(256) void stats_k(const float* __restrict__ lg,
                                               float* __restrict__ mxv, float* __restrict__ invv) {
  __shared__ float red[256];
  const int a = blockIdx.x, t = threadIdx.x;
  float m = -1e30f;
  for (int i = t; i < 800; i += 256) m = fmaxf(m, lg[a * 800 + i]);
  red[t] = m; __syncthreads();
  for (int s = 128; s >= 1; s >>= 1) { if (t < s) red[t] = fmaxf(red[t], red[t + s]); __syncthreads(); }
  const float mx = red[0];
  __syncthreads();
  float sum = 0.f;
  for (int i = t; i < 800; i += 256) sum += __expf(lg[a * 800 + i] - mx);
  red[t] = sum; __syncthreads();
  for (int s = 128; s >= 1; s >>= 1) { if (t < s) red[t] += red[t + s]; __syncthreads(); }
  if (t == 0) { mxv[a] = mx; invv[a] = 1.f / red[0]; }
}

__global__ __launch_bounds__(256) void attended_k(const unsigned short* __restrict__ emb,
                                                  const float* __restrict__ lg,
                                                  const float* __restrict__ mxv,
                                                  const float* __restrict__ invv,
                                                  float* __restrict__ attended) {
  const int b = blockIdx.x;
  const int a = b >> 3, chunk = b & 7;
  const int t = threadIdx.x;
  __shared__ float ws[100];
  const int i0 = chunk * 100;
  const float mx = mxv[a], inv = invv[a];
  if (t < 100) ws[t] = __expf(lg[a * 800 + i0 + t] - mx) * inv;
  __syncthreads();
  float acc = 0.f;
  const unsigned short* base = emb + ((size_t)(a * 800 + i0)) * 256 + t;
#pragma unroll 4
  for (int j = 0; j < 100; ++j) acc += ws[j] * b2f(base[(size_t)j * 256]);
  atomicAdd(&attended[a * 256 + t], acc);
}

__global__ __launch_bounds__(256) void cls_k(const float* __restrict__ attended,
                                             const unsigned short* __restrict__ params,
                                             void* __restrict__ out, const int* __restrict__ flag) {
  __shared__ float red[256];
  const int a = blockIdx.x, t = threadIdx.x;
  const float v = attended[a * 256 + t];
  const float p0 = v * b2f(params[P_WCLS + t * 2]);
  const float p1 = v * b2f(params[P_WCLS + t * 2 + 1]);
  red[t] = p0; __syncthreads();
  for (int s = 128; s >= 1; s >>= 1) { if (t < s) red[t] += red[t + s]; __syncthreads(); }
  const float r0 = red[0];
  __syncthreads();
  red[t] = p1; __syncthreads();
  for (int s = 128; s >= 1; s >>= 1) { if (t < s) red[t] += red[t + s]; __syncthreads(); }
  const float r1 = red[0];
  if (t == 0) {
    const float o0 = r0 + b2f(params[P_BCLS]);
    const float o1 = r1 + b2f(params[P_BCLS + 1]);
    if (*flag) {
      ((float*)out)[(size_t)NN * 256 + a * 2]     = o0;
      ((float*)out)[(size_t)NN * 256 + a * 2 + 1] = o1;
    } else {
      ((unsigned short*)out)[(size_t)NN * 256 + a * 2]     = f2b(o0);
      ((unsigned short*)out)[(size_t)NN * 256 + a * 2 + 1] = f2b(o1);
    }
  }
}

extern "C" void kernel_launch(void* const* d_in, const int* in_sizes, int n_in,
                              void* d_out, int out_size, void* d_ws, size_t ws_size,
                              hipStream_t stream) {
  (void)in_sizes; (void)n_in; (void)out_size; (void)ws_size;
  const void* x_raw  = d_in[0];
  const int*  eidx   = (const int*)d_in[1];
  // d_in[2] = batch (unused: audio = n / 800)
  const int* src = eidx;
  const int* dst = eidx + EE;

  char* ws = (char*)d_ws;
  size_t off = 0;
  auto alloc = [&](size_t bytes) -> void* {
    void* p = ws + off;
    off += (bytes + 255) & ~(size_t)255;
    return p;
  };
  int* flag              = (int*)alloc(256);
  unsigned short* params = (unsigned short*)alloc(4096 * 2);
  unsigned short* W1T    = (unsigned short*)alloc((size_t)512 * 512 * 2);
  unsigned short* W2T    = (unsigned short*)alloc((size_t)512 * 256 * 2);
  unsigned short* scr    = (unsigned short*)alloc((size_t)NN * 512 * 2);  // hrel + emb16
  unsigned short* hbig   = (unsigned short*)alloc((size_t)NN * 512 * 2);
  // --- contiguous zero region (all sizes multiples of 256 B) ---
  int*   counts   = (int*)alloc((size_t)NN * 4);               // 204800
  int*   cursor   = (int*)alloc((size_t)NN * 4);               // 204800
  float* attended = (float*)alloc((size_t)NUM_AUDIOS * 256 * 4); // 65536
  float* al_s1    = (float*)alloc((size_t)NN * 2 * 4);         // 409600
  float* al_d1    = (float*)alloc((size_t)NN * 2 * 4);
  float* al_s2    = (float*)alloc((size_t)NN * 2 * 4);
  float* al_d2    = (float*)alloc((size_t)NN * 2 * 4);         // total 2113536 B = ZERO_F4*16
  // --- end zero region ---
  int*   rowp   = (int*)alloc((size_t)NN * 4);
  int*   ssrc   = (int*)alloc((size_t)EE * 4);
  float* lg     = (float*)alloc((size_t)NN * 4);
  float* mxv    = (float*)alloc(NUM_AUDIOS * 4);
  float* invv   = (float*)alloc(NUM_AUDIOS * 4);
  unsigned short* hrel  = scr;                         // layer-1 relu output [NN,256]
  unsigned short* emb16 = scr + (size_t)NN * 256;      // node_emb [NN,256] (bf16 copy)

  prolog0_k<<<dim3(ZERO_BLOCKS), 256, 0, stream>>>((float4*)counts,
                                                   (const unsigned short*)x_raw, flag);

  prep_k<<<dim3(PB_HIST), 256, 0, stream>>>(
      d_in[3], W1T, d_in[7], W2T,
      d_in[4], d_in[5], d_in[6], d_in[8], d_in[9],
      d_in[10], d_in[11], d_in[12], d_in[13], d_in[14],
      params, dst, counts, flag);

  rowptr_k<<<dim3(NUM_AUDIOS), 256, 0, stream>>>(counts, rowp);
  scatter_k<<<dim3(EE / 256), 256, 0, stream>>>(src, dst, rowp, cursor, ssrc);

  // Layer 1 (x conversion fused into GEMM staging; al fused into epilogue)
  gemm_bt<<<dim3(1600), 256, 0, stream>>>(x_raw, W1T, hbig, 512, 512,
                                          params + P_AS1, params + P_AD1, al_s1, al_d1, flag);
  agg_k<<<dim3(NN / 4), 256, 0, stream>>>(hbig, al_s1, al_d1, rowp, counts, ssrc,
                                          params + P_B1, hrel, 1, nullptr, flag,
                                          params + P_WATT, nullptr);

  // Layer 2
  gemm_bt<<<dim3(1600), 256, 0, stream>>>(hrel, W2T, hbig, 256, 512,
                                          params + P_AS2, params + P_AD2, al_s2, al_d2, nullptr);
  agg_k<<<dim3(NN / 4), 256, 0, stream>>>(hbig, al_s2, al_d2, rowp, counts, ssrc,
                                          params + P_B2, emb16, 0, d_out, flag,
                                          params + P_WATT, lg);

  // Temporal attention + classifier
  stats_k<<<dim3(NUM_AUDIOS), 256, 0, stream>>>(lg, mxv, invv);
  attended_k<<<dim3(NUM_AUDIOS * 8), 256, 0, stream>>>(emb16, lg, mxv, invv, attended);
  cls_k<<<dim3(NUM_AUDIOS), 256, 0, stream>>>(attended, params, d_out, flag);
}

// Round 3
// 449.182 us; speedup vs baseline: 1.9165x; 1.9165x over previous
//
#include <hip/hip_runtime.h>
#include <cstdint>
#include <cstddef>

// Problem constants (fixed by the reference).
#define NUM_AUDIOS 64
#define NODES_PER  800
#define NN         51200
#define EE         409600
// IN_C=512, HID=256, OUT=256, HEADS=2 -> both GAT linears output [N, 512] (2 heads x 256)

typedef __attribute__((ext_vector_type(8))) unsigned short ushort8;
typedef __attribute__((ext_vector_type(4))) unsigned short ushort4v;
typedef __attribute__((ext_vector_type(8))) __bf16 bf16x8;
typedef __attribute__((ext_vector_type(4))) float f32x4;

__device__ __forceinline__ float b2f(unsigned short h) {
  return __uint_as_float(((unsigned)h) << 16);
}
__device__ __forceinline__ unsigned short f2b(float f) {
  unsigned u = __float_as_uint(f);
  u += 0x7fffu + ((u >> 16) & 1u);  // RNE
  return (unsigned short)(u >> 16);
}
__device__ __forceinline__ float lrelu(float v) { return v > 0.f ? v : 0.2f * v; }

// Canonical bf16 parameter block offsets (u16 units)
#define P_AS1 0
#define P_AD1 512
#define P_B1  1024
#define P_AS2 1536
#define P_AD2 2048
#define P_B2  2560
#define P_WATT 3072
#define P_BATT 3328
#define P_WCLS 3336
#define P_BCLS 3848

// Zero region: counts|cursor|attended|al_s1|al_d1|al_s2|al_d2 (contiguous, 2113536 B)
#define ZERO_F4 132096   // float4 count
#define ZERO_BLOCKS 516  // 516*256 = 132096

// ---------------- prolog: zero atomic buffers + dtype probe ----------------
__global__ __launch_bounds__(256) void prolog0_k(float4* __restrict__ zbase,
                                                 const unsigned short* __restrict__ x,
                                                 int* __restrict__ flag) {
  const int i = blockIdx.x * 256 + threadIdx.x;
  if (i < ZERO_F4) zbase[i] = (float4){0.f, 0.f, 0.f, 0.f};
  if (blockIdx.x == 0) {
    __shared__ int s;
    if (threadIdx.x == 0) s = 0;
    __syncthreads();
    int big = 0;
    for (int k = threadIdx.x; k < 4096; k += 256) {
      const float v = b2f(x[k]);
      if (!(__builtin_fabsf(v) <= 1e4f)) big = 1;  // catches >1e4, inf, NaN
    }
    if (big) atomicOr(&s, 1);
    __syncthreads();
    if (threadIdx.x == 0) *flag = s;  // 1 = fp32 inputs, 0 = bf16 inputs
  }
}

// ---------------- union prep: params | transpose W1 | transpose W2 | hist ------
#define PB_PAR  10
#define PB_T1   (PB_PAR + 1024)
#define PB_T2   (PB_T1 + 512)
#define PB_HIST (PB_T2 + 1600)   // total grid = 3146

__global__ __launch_bounds__(256) void prep_k(
    const void* __restrict__ W1, unsigned short* __restrict__ W1T,
    const void* __restrict__ W2, unsigned short* __restrict__ W2T,
    const void* p0, const void* p1, const void* p2, const void* p3, const void* p4,
    const void* p5, const void* p6, const void* p7, const void* p8, const void* p9,
    unsigned short* __restrict__ params,
    const int* __restrict__ dst, int* __restrict__ counts,
    const int* __restrict__ flagp) {
  const int b = blockIdx.x, tid = threadIdx.x;
  const int f = *flagp;
  if (b < PB_PAR) {                        // small params -> canonical bf16 block
    const void* srcs[10] = {p0, p1, p2, p3, p4, p5, p6, p7, p8, p9};
    const int offs[10] = {P_AS1, P_AD1, P_B1, P_AS2, P_AD2, P_B2, P_WATT, P_BATT, P_WCLS, P_BCLS};
    const int lens[10] = {512, 512, 256, 512, 512, 256, 256, 1, 512, 2};
    const int s = b;
    for (int i = tid; i < lens[s]; i += 256)
      params[offs[s] + i] = f ? f2b(((const float*)srcs[s])[i])
                              : ((const unsigned short*)srcs[s])[i];
  } else if (b < PB_T1) {                  // W1 [512,512] -> W1T
    const int idx = (b - PB_PAR) * 256 + tid;
    const int n = idx >> 9, k = idx & 511;
    W1T[idx] = f ? f2b(((const float*)W1)[(size_t)k * 512 + n])
                 : ((const unsigned short*)W1)[(size_t)k * 512 + n];
  } else if (b < PB_T2) {                  // W2 [256,512] -> W2T
    const int idx = (b - PB_T1) * 256 + tid;
    const int n = idx >> 8, k = idx & 255;
    W2T[idx] = f ? f2b(((const float*)W2)[(size_t)k * 512 + n])
                 : ((const unsigned short*)W2)[(size_t)k * 512 + n];
  } else {                                 // histogram of dst
    const int e = (b - PB_T2) * 256 + tid;
    atomicAdd(&counts[dst[e]], 1);
  }
}

// ---------------- CSR build ----------------
__global__ __launch_bounds__(256) void rowptr_k(const int* __restrict__ counts, int* __restrict__ row_ptr) {
  __shared__ int sh[800];
  __shared__ int pre[200];
  const int a = blockIdx.x, t = threadIdx.x;
  for (int i = t; i < 800; i += 256) sh[i] = counts[a * 800 + i];
  __syncthreads();
  if (t < 200) pre[t] = sh[t * 4] + sh[t * 4 + 1] + sh[t * 4 + 2] + sh[t * 4 + 3];
  __syncthreads();
  if (t == 0) {
    int run = 0;
    for (int i = 0; i < 200; ++i) { const int v = pre[i]; pre[i] = run; run += v; }
  }
  __syncthreads();
  if (t < 200) {
    int b = a * 6400 + pre[t];
#pragma unroll
    for (int j = 0; j < 4; ++j) { row_ptr[a * 800 + t * 4 + j] = b; b += sh[t * 4 + j]; }
  }
}

__global__ __launch_bounds__(256) void scatter_k(const int* __restrict__ src, const int* __restrict__ dst,
                                                 const int* __restrict__ row_ptr, int* __restrict__ cursor,
                                                 int* __restrict__ ssrc) {
  const int e = blockIdx.x * 256 + threadIdx.x;
  const int d = dst[e];
  const int p = atomicAdd(&cursor[d], 1);
  ssrc[row_ptr[d] + p] = src[e];
}

// ---------------- GEMM core fragment+MFMA step (XOR bank-deswizzle on read) ----
__device__ __forceinline__ void mfma_tile(const unsigned short* As, const unsigned short* Bs,
                                          int wm, int wn, int row, int quad, f32x4 acc[4][4]) {
  bf16x8 af[4], bq[4];
  const int pa = (quad ^ (row & 3)) * 8;  // physical k-chunk (bank swizzle)
#pragma unroll
  for (int i = 0; i < 4; ++i) {
    af[i] = *(const bf16x8*)&As[(wm * 64 + i * 16 + row) * 32 + pa];
    bq[i] = *(const bf16x8*)&Bs[(wn * 64 + i * 16 + row) * 32 + pa];
  }
#pragma unroll
  for (int i = 0; i < 4; ++i)
#pragma unroll
    for (int j = 0; j < 4; ++j)
      acc[i][j] = __builtin_amdgcn_mfma_f32_16x16x32_bf16(af[i], bq[j], acc[i][j], 0, 0, 0);
}

// ---------------- GEMM + fused attention-logit partials ----------------
// C[M,512] = A[M,K] @ B (BT[512,K]). 128x128 tile, mfma 16x16x32 bf16.
// bf16 path: double-buffered LDS (2x16KB), STAGE(next) -> vmcnt(4) -> barrier
// -> MFMA(cur) -> barrier. Counted vmcnt keeps next-tile loads in flight across
// barriers (T3/T4-lite). fp32 path: round-1 single-buffer structure.
// Epilogue: C tile staged in LDS with XOR-chunk swizzle (static acc indexing
// ONLY - rule #20), then coalesced 16B global stores.
__global__ __launch_bounds__(256) void gemm_bt(const void* __restrict__ Araw,
                                               const unsigned short* __restrict__ BT,
                                               unsigned short* __restrict__ C,
                                               int K, int Nn,
                                               const unsigned short* __restrict__ a_s,
                                               const unsigned short* __restrict__ a_d,
                                               float* __restrict__ al_s,
                                               float* __restrict__ al_d,
                                               const int* __restrict__ aflag) {
  __shared__ unsigned short smem[16384];   // 32KB: dbuf K-loop; epilogue reuses all
  const int tid = threadIdx.x;
  const int wave = tid >> 6, lane = tid & 63;
  const int bid = blockIdx.x;
  const int g = bid & 7, bt = bid >> 3;              // 8 XCDs x 200 blocks
  const int m0 = (g * 50 + (bt >> 2)) * 128;         // 50 row-blocks per XCD
  const int n0 = (bt & 3) * 128;                     // columns innermost
  const int wm = wave >> 1, wn = wave & 1;
  const int row = lane & 15, quad = lane >> 4;
  f32x4 acc[4][4];
#pragma unroll
  for (int i = 0; i < 4; ++i)
#pragma unroll
    for (int j = 0; j < 4; ++j) acc[i][j] = (f32x4){0.f, 0.f, 0.f, 0.f};

  const bool a_is_f32 = (aflag != nullptr) && (*aflag != 0);
  const unsigned short* A16 = (const unsigned short*)Araw;
  const float* A32 = (const float*)Araw;
  // staging index: chunk cc = r*256+tid; row = cc>>2; physical k-slot = cc&3;
  // global (logical) k-chunk = (cc&3) ^ (row&3)
  const int srow0 = tid >> 2;                        // r=0 row; r=1 row = +64
  const int kph = tid & 3;

  if (!a_is_f32) {
    const int nk = K >> 5;
    auto stage = [&](int buf, int k0) {
      unsigned short* Asb = smem + buf * 8192;
      unsigned short* Bsb = Asb + 4096;
#pragma unroll
      for (int r = 0; r < 2; ++r) {
        const int arow = r * 64 + srow0;
        const int kc = ((kph ^ (arow & 3)) * 8);
        __builtin_amdgcn_global_load_lds(
            (const __attribute__((address_space(1))) void*)(A16 + (size_t)(m0 + arow) * K + k0 + kc),
            (__attribute__((address_space(3))) void*)(Asb + (r * 256 + wave * 64) * 8),
            16, 0, 0);
        __builtin_amdgcn_global_load_lds(
            (const __attribute__((address_space(1))) void*)(BT + (size_t)(n0 + arow) * K + k0 + kc),
            (__attribute__((address_space(3))) void*)(Bsb + (r * 256 + wave * 64) * 8),
            16, 0, 0);
      }
    };
    stage(0, 0);                          // prologue: tile 0 in flight (4 loads)
    for (int t = 0; t < nk; ++t) {
      const int cur = t & 1;
      if (t + 1 < nk) {
        stage(cur ^ 1, (t + 1) << 5);     // next tile: 4 newer loads in flight
        asm volatile("s_waitcnt vmcnt(4)" ::: "memory");  // wait only cur tile
      } else {
        asm volatile("s_waitcnt vmcnt(0)" ::: "memory");
      }
      __builtin_amdgcn_sched_barrier(0);
      __builtin_amdgcn_s_barrier();       // all waves: cur tile landed
      __builtin_amdgcn_sched_barrier(0);
      mfma_tile(smem + cur * 8192, smem + cur * 8192 + 4096, wm, wn, row, quad, acc);
      __builtin_amdgcn_sched_barrier(0);
      __builtin_amdgcn_s_barrier();       // all waves done reading cur -> reusable
    }
  } else {
    unsigned short* As = smem;
    unsigned short* Bs = smem + 4096;
    for (int k0 = 0; k0 < K; k0 += 32) {
      ushort8 pk[2];
#pragma unroll
      for (int r = 0; r < 2; ++r) {
        const int arow = r * 64 + srow0;
        const int kc = ((kph ^ (arow & 3)) * 8);
        const float* p = A32 + (size_t)(m0 + arow) * K + k0 + kc;
        const float4 f0 = *(const float4*)p;
        const float4 f1 = *(const float4*)(p + 4);
        pk[r][0] = f2b(f0.x); pk[r][1] = f2b(f0.y); pk[r][2] = f2b(f0.z); pk[r][3] = f2b(f0.w);
        pk[r][4] = f2b(f1.x); pk[r][5] = f2b(f1.y); pk[r][6] = f2b(f1.z); pk[r][7] = f2b(f1.w);
      }
      __syncthreads();  // previous iteration's LDS readers done
#pragma unroll
      for (int r = 0; r < 2; ++r) {
        const int arow = r * 64 + srow0;
        const int kc = ((kph ^ (arow & 3)) * 8);
        __builtin_amdgcn_global_load_lds(
            (const __attribute__((address_space(1))) void*)(BT + (size_t)(n0 + arow) * K + k0 + kc),
            (__attribute__((address_space(3))) void*)(Bs + (size_t)(r * 256 + wave * 64) * 8),
            16, 0, 0);
        *(ushort8*)&As[(size_t)(r * 256 + tid) * 8] = pk[r];
      }
      __syncthreads();  // ds_writes visible + B DMA drained (vmcnt0 before barrier)
      mfma_tile(As, Bs, wm, wn, row, quad, acc);
    }
  }

  // ---------------- epilogue: LDS-staged coalesced C store ----------------
  // C/D layout (verified m89/m91): col = lane&15, row = quad*4 + reg
  // LDS physical layout: row rl, logical 16-ushort chunk lc stored at chunk
  // lc ^ ((rl>>2)&3). Writer: (rl>>2)&3 == quad -> 4 quads hit 4 distinct bank
  // octets (full 32-bank spread, 2 lanes/bank same word = free). Reader XOR is
  // wave-uniform. All acc indices are compile-time constants (rule #20).
  const int col = lane & 15;
  __syncthreads();  // all mfma LDS readers done before smem is overwritten
  {
#pragma unroll
    for (int i = 0; i < 4; ++i)
#pragma unroll
      for (int jj = 0; jj < 4; ++jj) {
#pragma unroll
        for (int r = 0; r < 4; ++r) {
          const int rl = wm * 64 + i * 16 + quad * 4 + r;
          const int pc = (wn * 4 + jj) ^ quad;   // physical chunk (address-only swizzle)
          smem[rl * 128 + pc * 16 + col] = f2b(acc[i][jj][r]);
        }
      }
  }
  __syncthreads();
  {
    const int rloc = tid >> 4;           // 0..15
    const int c8 = (tid & 15) * 8;       // logical ushort col base, 16B aligned
    const int lc = c8 >> 4;              // logical chunk
    const int coff = c8 & 15;            // 0 or 8
#pragma unroll
    for (int s = 0; s < 8; ++s) {
      const int rl = s * 16 + rloc;
      const int q = (rl >> 2) & 3;       // wave-uniform (= (rloc>>2)&3)
      const ushort8 v = *(const ushort8*)&smem[rl * 128 + (lc ^ q) * 16 + coff];
      *(ushort8*)&C[(size_t)(m0 + rl) * Nn + n0 + c8] = v;
    }
  }

  // Fused al partials: head = gn>>8 is wave-uniform (n0+wn*64 multiple of 64).
  {
    const int head = (n0 + wn * 64) >> 8;
    float as4[4], ad4[4];
#pragma unroll
    for (int j = 0; j < 4; ++j) {
      const int gn = n0 + wn * 64 + j * 16 + col;
      as4[j] = b2f(a_s[gn]);
      ad4[j] = b2f(a_d[gn]);
    }
#pragma unroll
    for (int i = 0; i < 4; ++i)
#pragma unroll
      for (int r = 0; r < 4; ++r) {
        float ps = 0.f, pd = 0.f;
#pragma unroll
        for (int j = 0; j < 4; ++j) { ps += acc[i][j][r] * as4[j]; pd += acc[i][j][r] * ad4[j]; }
#pragma unroll
        for (int off = 1; off < 16; off <<= 1) {  // reduce the 16 lanes sharing this row
          ps += __shfl_xor(ps, off);
          pd += __shfl_xor(pd, off);
        }
        if (col == 0) {
          const int gm = m0 + wm * 64 + i * 16 + quad * 4 + r;
          atomicAdd(&al_s[gm * 2 + head], ps);
          atomicAdd(&al_d[gm * 2 + head], pd);
        }
      }
  }
}

// ---------------- GAT aggregate: one wave per node, XCD-pinned audios ----------
// Edge-parallel scoring; per-edge w,s broadcast via __shfl. lrelu monotone =>
// max e_i = lrelu(max al_s_i + ald). Optional lg: fused temporal logits.
__global__ __launch_bounds__(256) void agg_k(const unsigned short* __restrict__ h,
                                             const float* __restrict__ al_s, const float* __restrict__ al_d,
                                             const int* __restrict__ row_ptr, const int* __restrict__ counts,
                                             const int* __restrict__ ssrc, const unsigned short* __restrict__ bias,
                                             unsigned short* __restrict__ out, int do_relu,
                                             void* __restrict__ out2, const int* __restrict__ flagp,
                                             const unsigned short* __restrict__ watt,
                                             float* __restrict__ lg) {
  const int wave = threadIdx.x >> 6, lane = threadIdx.x & 63;
  const int b = blockIdx.x;
  const int g = b & 7, r = b >> 3;          // g ~ XCD id (round-robin dispatch)
  const int a = g + 8 * (r / 200);          // audio pinned to XCD g
  const int chunk = r % 200;
  const int n = a * 800 + chunk * 4 + wave;
  const int head = lane >> 5;               // lanes 0-31: head0, 32-63: head1
  const int hl = lane & 31;
  const int hsel = lane & 32;
  const int deg = counts[n];
  const int base = row_ptr[n];
  const float ald = al_d[n * 2 + head];
  const float self_e = lrelu(al_s[n * 2 + head] + ald);

  float m = -1e30f;
  for (int i = hl; i < deg; i += 32) {
    const int s = ssrc[base + i];
    m = fmaxf(m, al_s[s * 2 + head]);
  }
#pragma unroll
  for (int off = 1; off < 32; off <<= 1) m = fmaxf(m, __shfl_xor(m, off));
  const float mx = fmaxf(lrelu(m + ald), self_e);

  const float w_self = __expf(self_e - mx);
  float acc[8];
  {
    const ushort8 hv = *(const ushort8*)&h[(unsigned)(n * 512 + lane * 8)];
#pragma unroll
    for (int j = 0; j < 8; ++j) acc[j] = w_self * b2f(hv[j]);
  }
  float dpart = 0.f;
  for (int t0 = 0; t0 < deg; t0 += 32) {
    const int cnt = min(32, deg - t0);
    int s = 0; float w = 0.f;
    if (hl < cnt) {
      s = ssrc[base + t0 + hl];
      w = __expf(lrelu(al_s[s * 2 + head] + ald) - mx);
      dpart += w;
    }
    for (int i = 0; i < cnt; ++i) {
      const float wb = __shfl(w, hsel + i);
      const int sb = __shfl(s, hsel + i);
      const ushort8 hv = *(const ushort8*)&h[(unsigned)(sb * 512 + lane * 8)];
#pragma unroll
      for (int j = 0; j < 8; ++j) acc[j] += wb * b2f(hv[j]);
    }
  }
#pragma unroll
  for (int off = 1; off < 32; off <<= 1) dpart += __shfl_xor(dpart, off);
  const float inv = 1.f / (w_self + dpart);

  const int c0 = hl * 8;
  ushort8 res;
  float ov[8];
#pragma unroll
  for (int j = 0; j < 8; ++j) {
    const float mine = acc[j] * inv;
    const float other = __shfl_xor(mine, 32);  // partner lane: other head, same cols
    float o = (mine + other) * 0.5f + b2f(bias[c0 + j]);
    if (do_relu) o = fmaxf(o, 0.f);
    ov[j] = o;
    res[j] = f2b(o);
  }
  if (lane < 32) {
    *(ushort8*)&out[(unsigned)(n * 256 + c0)] = res;
    if (out2) {
      if (*flagp) {
        float4* p = (float4*)((float*)out2 + (size_t)n * 256 + c0);
        p[0] = (float4){ov[0], ov[1], ov[2], ov[3]};
        p[1] = (float4){ov[4], ov[5], ov[6], ov[7]};
      } else {
        *(ushort8*)((unsigned short*)out2 + (size_t)n * 256 + c0) = res;
      }
    }
    if (lg) {  // fused temporal logits: dot(out_row, w_att) + b_att
      const ushort8 wv = *(const ushort8*)&watt[c0];
      float d = 0.f;
#pragma unroll
      for (int j = 0; j < 8; ++j) d += ov[j] * b2f(wv[j]);
#pragma unroll
      for (int off = 1; off < 32; off <<= 1) d += __shfl_xor(d, off);
      if (hl == 0) lg[n] = d + b2f(watt[256]);  // b_att sits right after w_att
    }
  }
}

// ---------------- temporal attention, grid-parallel ----------------
__global__ __launch_bounds__(256) void stats_k(const float* __restrict__ lg,
                                               float* __restrict__ mxv, float* __restrict__ invv) {
  __shared__ float red[256];
  const int a = blockIdx.x, t = threadIdx.x;
  float m = -1e30f;
  for (int i = t; i < 800; i += 256) m = fmaxf(m, lg[a * 800 + i]);
  red[t] = m; __syncthreads();
  for (int s = 128; s >= 1; s >>= 1) { if (t < s) red[t] = fmaxf(red[t], red[t + s]); __syncthreads(); }
  const float mx = red[0];
  __syncthreads();
  float sum = 0.f;
  for (int i = t; i < 800; i += 256) sum += __expf(lg[a * 800 + i] - mx);
  red[t] = sum; __syncthreads();
  for (int s = 128; s >= 1; s >>= 1) { if (t < s) red[t] += red[t + s]; __syncthreads(); }
  if (t == 0) { mxv[a] = mx; invv[a] = 1.f / red[0]; }
}

__global__ __launch_bounds__(256) void attended_k(const unsigned short* __restrict__ emb,
                                                  const float* __restrict__ lg,
                                                  const float* __restrict__ mxv,
                                                  const float* __restrict__ invv,
                                                  float* __restrict__ attended) {
  const int b = blockIdx.x;
  const int a = b >> 3, chunk = b & 7;
  const int t = threadIdx.x;
  __shared__ float ws[100];
  const int i0 = chunk * 100;
  const float mx = mxv[a], inv = invv[a];
  if (t < 100) ws[t] = __expf(lg[a * 800 + i0 + t] - mx) * inv;
  __syncthreads();
  float acc = 0.f;
  const unsigned short* base = emb + ((size_t)(a * 800 + i0)) * 256 + t;
#pragma unroll 4
  for (int j = 0; j < 100; ++j) acc += ws[j] * b2f(base[(size_t)j * 256]);
  atomicAdd(&attended[a * 256 + t], acc);
}

__global__ __launch_bounds__(256) void cls_k(const float* __restrict__ attended,
                                             const unsigned short* __restrict__ params,
                                             void* __restrict__ out, const int* __restrict__ flag) {
  __shared__ float red[256];
  const int a = blockIdx.x, t = threadIdx.x;
  const float v = attended[a * 256 + t];
  const float p0 = v * b2f(params[P_WCLS + t * 2]);
  const float p1 = v * b2f(params[P_WCLS + t * 2 + 1]);
  red[t] = p0; __syncthreads();
  for (int s = 128; s >= 1; s >>= 1) { if (t < s) red[t] += red[t + s]; __syncthreads(); }
  const float r0 = red[0];
  __syncthreads();
  red[t] = p1; __syncthreads();
  for (int s = 128; s >= 1; s >>= 1) { if (t < s) red[t] += red[t + s]; __syncthreads(); }
  const float r1 = red[0];
  if (t == 0) {
    const float o0 = r0 + b2f(params[P_BCLS]);
    const float o1 = r1 + b2f(params[P_BCLS + 1]);
    if (*flag) {
      ((float*)out)[(size_t)NN * 256 + a * 2]     = o0;
      ((float*)out)[(size_t)NN * 256 + a * 2 + 1] = o1;
    } else {
      ((unsigned short*)out)[(size_t)NN * 256 + a * 2]     = f2b(o0);
      ((unsigned short*)out)[(size_t)NN * 256 + a * 2 + 1] = f2b(o1);
    }
  }
}

extern "C" void kernel_launch(void* const* d_in, const int* in_sizes, int n_in,
                              void* d_out, int out_size, void* d_ws, size_t ws_size,
                              hipStream_t stream) {
  (void)in_sizes; (void)n_in; (void)out_size; (void)ws_size;
  const void* x_raw  = d_in[0];
  const int*  eidx   = (const int*)d_in[1];
  // d_in[2] = batch (unused: audio = n / 800)
  const int* src = eidx;
  const int* dst = eidx + EE;

  char* ws = (char*)d_ws;
  size_t off = 0;
  auto alloc = [&](size_t bytes) -> void* {
    void* p = ws + off;
    off += (bytes + 255) & ~(size_t)255;
    return p;
  };
  int* flag              = (int*)alloc(256);
  unsigned short* params = (unsigned short*)alloc(4096 * 2);
  unsigned short* W1T    = (unsigned short*)alloc((size_t)512 * 512 * 2);
  unsigned short* W2T    = (unsigned short*)alloc((size_t)512 * 256 * 2);
  unsigned short* scr    = (unsigned short*)alloc((size_t)NN * 512 * 2);  // hrel + emb16
  unsigned short* hbig   = (unsigned short*)alloc((size_t)NN * 512 * 2);
  // --- contiguous zero region (all sizes multiples of 256 B) ---
  int*   counts   = (int*)alloc((size_t)NN * 4);               // 204800
  int*   cursor   = (int*)alloc((size_t)NN * 4);               // 204800
  float* attended = (float*)alloc((size_t)NUM_AUDIOS * 256 * 4); // 65536
  float* al_s1    = (float*)alloc((size_t)NN * 2 * 4);         // 409600
  float* al_d1    = (float*)alloc((size_t)NN * 2 * 4);
  float* al_s2    = (float*)alloc((size_t)NN * 2 * 4);
  float* al_d2    = (float*)alloc((size_t)NN * 2 * 4);         // total 2113536 B = ZERO_F4*16
  // --- end zero region ---
  int*   rowp   = (int*)alloc((size_t)NN * 4);
  int*   ssrc   = (int*)alloc((size_t)EE * 4);
  float* lg     = (float*)alloc((size_t)NN * 4);
  float* mxv    = (float*)alloc(NUM_AUDIOS * 4);
  float* invv   = (float*)alloc(NUM_AUDIOS * 4);
  unsigned short* hrel  = scr;                         // layer-1 relu output [NN,256]
  unsigned short* emb16 = scr + (size_t)NN * 256;      // node_emb [NN,256] (bf16 copy)

  prolog0_k<<<dim3(ZERO_BLOCKS), 256, 0, stream>>>((float4*)counts,
                                                   (const unsigned short*)x_raw, flag);

  prep_k<<<dim3(PB_HIST), 256, 0, stream>>>(
      d_in[3], W1T, d_in[7], W2T,
      d_in[4], d_in[5], d_in[6], d_in[8], d_in[9],
      d_in[10], d_in[11], d_in[12], d_in[13], d_in[14],
      params, dst, counts, flag);

  rowptr_k<<<dim3(NUM_AUDIOS), 256, 0, stream>>>(counts, rowp);
  scatter_k<<<dim3(EE / 256), 256, 0, stream>>>(src, dst, rowp, cursor, ssrc);

  // Layer 1 (x conversion fused into GEMM staging; al fused into epilogue)
  gemm_bt<<<dim3(1600), 256, 0, stream>>>(x_raw, W1T, hbig, 512, 512,
                                          params + P_AS1, params + P_AD1, al_s1, al_d1, flag);
  agg_k<<<dim3(NN / 4), 256, 0, stream>>>(hbig, al_s1, al_d1, rowp, counts, ssrc,
                                          params + P_B1, hrel, 1, nullptr, flag,
                                          params + P_WATT, nullptr);

  // Layer 2
  gemm_bt<<<dim3(1600), 256, 0, stream>>>(hrel, W2T, hbig, 256, 512,
                                          params + P_AS2, params + P_AD2, al_s2, al_d2, nullptr);
  agg_k<<<dim3(NN / 4), 256, 0, stream>>>(hbig, al_s2, al_d2, rowp, counts, ssrc,
                                          params + P_B2, emb16, 0, d_out, flag,
                                          params + P_WATT, lg);

  // Temporal attention + classifier
  stats_k<<<dim3(NUM_AUDIOS), 256, 0, stream>>>(lg, mxv, invv);
  attended_k<<<dim3(NUM_AUDIOS * 8), 256, 0, stream>>>(emb16, lg, mxv, invv, attended);
  cls_k<<<dim3(NUM_AUDIOS), 256, 0, stream>>>(attended, params, d_out, flag);
}

// Round 4
// 426.632 us; speedup vs baseline: 2.0178x; 1.0529x over previous
//
#include <hip/hip_runtime.h>
#include <cstdint>
#include <cstddef>

// Problem constants (fixed by the reference).
#define NUM_AUDIOS 64
#define NODES_PER  800
#define NN         51200
#define EE         409600
// IN_C=512, HID=256, OUT=256, HEADS=2 -> both GAT linears output [N, 512] (2 heads x 256)

typedef __attribute__((ext_vector_type(8))) unsigned short ushort8;
typedef __attribute__((ext_vector_type(8))) __bf16 bf16x8;
typedef __attribute__((ext_vector_type(4))) float f32x4;

__device__ __forceinline__ float b2f(unsigned short h) {
  return __uint_as_float(((unsigned)h) << 16);
}
__device__ __forceinline__ unsigned short f2b(float f) {
  unsigned u = __float_as_uint(f);
  u += 0x7fffu + ((u >> 16) & 1u);  // RNE
  return (unsigned short)(u >> 16);
}
__device__ __forceinline__ float lrelu(float v) { return v > 0.f ? v : 0.2f * v; }

// Canonical bf16 parameter block offsets (u16 units)
#define P_AS1 0
#define P_AD1 512
#define P_B1  1024
#define P_AS2 1536
#define P_AD2 2048
#define P_B2  2560
#define P_WATT 3072
#define P_BATT 3328
#define P_WCLS 3336
#define P_BCLS 3848

// Zero region: counts|cursor|attended|al_s1|al_d1|al_s2|al_d2 (contiguous, 2113536 B)
#define ZERO_F4 132096   // float4 count
#define ZERO_BLOCKS 516  // 516*256 = 132096

// ---------------- prolog: zero atomic buffers + dtype probe ----------------
__global__ __launch_bounds__(256) void prolog0_k(float4* __restrict__ zbase,
                                                 const unsigned short* __restrict__ x,
                                                 int* __restrict__ flag) {
  const int i = blockIdx.x * 256 + threadIdx.x;
  if (i < ZERO_F4) zbase[i] = (float4){0.f, 0.f, 0.f, 0.f};
  if (blockIdx.x == 0) {
    __shared__ int s;
    if (threadIdx.x == 0) s = 0;
    __syncthreads();
    int big = 0;
    for (int k = threadIdx.x; k < 4096; k += 256) {
      const float v = b2f(x[k]);
      if (!(__builtin_fabsf(v) <= 1e4f)) big = 1;  // catches >1e4, inf, NaN
    }
    if (big) atomicOr(&s, 1);
    __syncthreads();
    if (threadIdx.x == 0) *flag = s;  // 1 = fp32 inputs, 0 = bf16 inputs
  }
}

// ---------------- union prep: params | transpose W1 | transpose W2 | hist ------
#define PB_PAR  10
#define PB_T1   (PB_PAR + 1024)
#define PB_T2   (PB_T1 + 512)
#define PB_HIST (PB_T2 + 1600)   // total grid = 3146

__global__ __launch_bounds__(256) void prep_k(
    const void* __restrict__ W1, unsigned short* __restrict__ W1T,
    const void* __restrict__ W2, unsigned short* __restrict__ W2T,
    const void* p0, const void* p1, const void* p2, const void* p3, const void* p4,
    const void* p5, const void* p6, const void* p7, const void* p8, const void* p9,
    unsigned short* __restrict__ params,
    const int* __restrict__ dst, int* __restrict__ counts,
    const int* __restrict__ flagp) {
  const int b = blockIdx.x, tid = threadIdx.x;
  const int f = *flagp;
  if (b < PB_PAR) {                        // small params -> canonical bf16 block
    const void* srcs[10] = {p0, p1, p2, p3, p4, p5, p6, p7, p8, p9};
    const int offs[10] = {P_AS1, P_AD1, P_B1, P_AS2, P_AD2, P_B2, P_WATT, P_BATT, P_WCLS, P_BCLS};
    const int lens[10] = {512, 512, 256, 512, 512, 256, 256, 1, 512, 2};
    const int s = b;
    for (int i = tid; i < lens[s]; i += 256)
      params[offs[s] + i] = f ? f2b(((const float*)srcs[s])[i])
                              : ((const unsigned short*)srcs[s])[i];
  } else if (b < PB_T1) {                  // W1 [512,512] -> W1T
    const int idx = (b - PB_PAR) * 256 + tid;
    const int n = idx >> 9, k = idx & 511;
    W1T[idx] = f ? f2b(((const float*)W1)[(size_t)k * 512 + n])
                 : ((const unsigned short*)W1)[(size_t)k * 512 + n];
  } else if (b < PB_T2) {                  // W2 [256,512] -> W2T
    const int idx = (b - PB_T1) * 256 + tid;
    const int n = idx >> 8, k = idx & 255;
    W2T[idx] = f ? f2b(((const float*)W2)[(size_t)k * 512 + n])
                 : ((const unsigned short*)W2)[(size_t)k * 512 + n];
  } else {                                 // histogram of dst
    const int e = (b - PB_T2) * 256 + tid;
    atomicAdd(&counts[dst[e]], 1);
  }
}

// ---------------- CSR build ----------------
__global__ __launch_bounds__(256) void rowptr_k(const int* __restrict__ counts, int* __restrict__ row_ptr) {
  __shared__ int sh[800];
  __shared__ int pre[200];
  const int a = blockIdx.x, t = threadIdx.x;
  for (int i = t; i < 800; i += 256) sh[i] = counts[a * 800 + i];
  __syncthreads();
  if (t < 200) pre[t] = sh[t * 4] + sh[t * 4 + 1] + sh[t * 4 + 2] + sh[t * 4 + 3];
  __syncthreads();
  if (t == 0) {
    int run = 0;
    for (int i = 0; i < 200; ++i) { const int v = pre[i]; pre[i] = run; run += v; }
  }
  __syncthreads();
  if (t < 200) {
    int b = a * 6400 + pre[t];
#pragma unroll
    for (int j = 0; j < 4; ++j) { row_ptr[a * 800 + t * 4 + j] = b; b += sh[t * 4 + j]; }
  }
}

__global__ __launch_bounds__(256) void scatter_k(const int* __restrict__ src, const int* __restrict__ dst,
                                                 const int* __restrict__ row_ptr, int* __restrict__ cursor,
                                                 int* __restrict__ ssrc) {
  const int e = blockIdx.x * 256 + threadIdx.x;
  const int d = dst[e];
  const int p = atomicAdd(&cursor[d], 1);
  ssrc[row_ptr[d] + p] = src[e];
}

// ---------------- 256x256 GEMM core: 8 waves (2m x 4n), wave = 128x64 ----------
__device__ __forceinline__ void mfma_tile256(const unsigned short* As, const unsigned short* Bs,
                                             int wm, int wn, int row, int quad, f32x4 acc[8][4]) {
  bf16x8 af[8], bq[4];
  const int pa = (quad ^ (row & 3)) * 8;  // physical k-chunk (bank swizzle)
#pragma unroll
  for (int i = 0; i < 8; ++i)
    af[i] = *(const bf16x8*)&As[(wm * 128 + i * 16 + row) * 32 + pa];
#pragma unroll
  for (int j = 0; j < 4; ++j)
    bq[j] = *(const bf16x8*)&Bs[(wn * 64 + j * 16 + row) * 32 + pa];
#pragma unroll
  for (int i = 0; i < 8; ++i)
#pragma unroll
    for (int j = 0; j < 4; ++j)
      acc[i][j] = __builtin_amdgcn_mfma_f32_16x16x32_bf16(af[i], bq[j], acc[i][j], 0, 0, 0);
}

// ---------------- GEMM + fused attention-logit partials ----------------
// C[M,512] = A[M,K] @ B (BT[512,K]). 256x256 tile, 512 threads, 8 waves.
// n-tile = 256 cols = exactly one head -> al_s/al_d computed with PLAIN stores
// (block-local LDS reduction across the 4 n-waves). NO atomics.
// bf16 path: double-buffered LDS (2x32KB), counted vmcnt(4). fp32 path
// (*aflag==1): VGPR load+convert A, DMA B, single-buffered.
// Epilogue: C staged via LDS in two 128-row halves, coalesced 16B stores.
__global__ __launch_bounds__(512, 2) void gemm_bt(const void* __restrict__ Araw,
                                                  const unsigned short* __restrict__ BT,
                                                  unsigned short* __restrict__ C,
                                                  int K, int Nn,
                                                  const unsigned short* __restrict__ a_s,
                                                  const unsigned short* __restrict__ a_d,
                                                  float* __restrict__ al_s,
                                                  float* __restrict__ al_d,
                                                  const int* __restrict__ aflag) {
  __shared__ unsigned short smem[32768];   // 64KB: dbuf K-loop; epilogue reuses
  const int tid = threadIdx.x;
  const int wave = tid >> 6, lane = tid & 63;
  const int bid = blockIdx.x;
  const int g = bid & 7, bt = bid >> 3;              // 8 XCDs x 50 blocks
  const int mt = bt >> 1, nt = bt & 1;               // 25 m-tiles/XCD, nt innermost
  const int m0 = (g * 25 + mt) * 256;
  const int n0 = nt * 256;                           // head = nt
  const int wm = wave >> 2, wn = wave & 3;
  const int row = lane & 15, quad = lane >> 4;
  const int col = lane & 15;
  f32x4 acc[8][4];
#pragma unroll
  for (int i = 0; i < 8; ++i)
#pragma unroll
    for (int j = 0; j < 4; ++j) acc[i][j] = (f32x4){0.f, 0.f, 0.f, 0.f};

  const bool a_is_f32 = (aflag != nullptr) && (*aflag != 0);
  const unsigned short* A16 = (const unsigned short*)Araw;
  const float* A32 = (const float*)Araw;
  // staging: chunk cc = p*512+tid; LDS row = cc>>2; physical k-slot = cc&3;
  // global k-chunk = (cc&3) ^ (row&3)   [XOR bank swizzle, matches mfma reads]
  const int srow0 = tid >> 2;                        // 0..127; pass p adds 128
  const int kph = tid & 3;

  if (!a_is_f32) {
    const int nk = K >> 5;
    auto stage = [&](int buf, int k0) {
      unsigned short* Asb = smem + buf * 16384;      // 16KB A
      unsigned short* Bsb = Asb + 8192;              // 16KB B
#pragma unroll
      for (int p = 0; p < 2; ++p) {
        const int arow = p * 128 + srow0;
        const int kc = ((kph ^ (arow & 3)) * 8);
        __builtin_amdgcn_global_load_lds(
            (const __attribute__((address_space(1))) void*)(A16 + (size_t)(m0 + arow) * K + k0 + kc),
            (__attribute__((address_space(3))) void*)(Asb + (p * 512 + tid) * 8),
            16, 0, 0);
        __builtin_amdgcn_global_load_lds(
            (const __attribute__((address_space(1))) void*)(BT + (size_t)(n0 + arow) * K + k0 + kc),
            (__attribute__((address_space(3))) void*)(Bsb + (p * 512 + tid) * 8),
            16, 0, 0);
      }
    };
    stage(0, 0);                          // prologue: tile 0 in flight (4 loads/wave)
    for (int t = 0; t < nk; ++t) {
      const int cur = t & 1;
      if (t + 1 < nk) {
        stage(cur ^ 1, (t + 1) << 5);     // next tile: 4 newer loads in flight
        asm volatile("s_waitcnt vmcnt(4)" ::: "memory");  // wait only cur tile
      } else {
        asm volatile("s_waitcnt vmcnt(0)" ::: "memory");
      }
      __builtin_amdgcn_sched_barrier(0);
      __builtin_amdgcn_s_barrier();       // all waves: cur tile landed
      __builtin_amdgcn_sched_barrier(0);
      mfma_tile256(smem + cur * 16384, smem + cur * 16384 + 8192, wm, wn, row, quad, acc);
      __builtin_amdgcn_sched_barrier(0);
      __builtin_amdgcn_s_barrier();       // all waves done reading cur -> reusable
    }
  } else {
    unsigned short* As = smem;            // single-buffered
    unsigned short* Bs = smem + 8192;
    for (int k0 = 0; k0 < K; k0 += 32) {
      ushort8 pk[2];
#pragma unroll
      for (int p = 0; p < 2; ++p) {
        const int arow = p * 128 + srow0;
        const int kc = ((kph ^ (arow & 3)) * 8);
        const float* ap = A32 + (size_t)(m0 + arow) * K + k0 + kc;
        const float4 f0 = *(const float4*)ap;
        const float4 f1 = *(const float4*)(ap + 4);
        pk[p][0] = f2b(f0.x); pk[p][1] = f2b(f0.y); pk[p][2] = f2b(f0.z); pk[p][3] = f2b(f0.w);
        pk[p][4] = f2b(f1.x); pk[p][5] = f2b(f1.y); pk[p][6] = f2b(f1.z); pk[p][7] = f2b(f1.w);
      }
      __syncthreads();  // previous iteration's LDS readers done
#pragma unroll
      for (int p = 0; p < 2; ++p) {
        const int arow = p * 128 + srow0;
        const int kc = ((kph ^ (arow & 3)) * 8);
        __builtin_amdgcn_global_load_lds(
            (const __attribute__((address_space(1))) void*)(BT + (size_t)(n0 + arow) * K + k0 + kc),
            (__attribute__((address_space(3))) void*)(Bs + (size_t)(p * 512 + tid) * 8),
            16, 0, 0);
        *(ushort8*)&As[(size_t)(p * 512 + tid) * 8] = pk[p];
      }
      __syncthreads();  // ds_writes visible + B DMA drained (vmcnt0 before barrier)
      mfma_tile256(As, Bs, wm, wn, row, quad, acc);
    }
  }

  // ---------------- epilogue ----------------
  __syncthreads();  // all K-loop LDS readers done before smem reuse

  // (1) al partials -> LDS -> plain global stores (block owns m-rows x head nt)
  {
    float* alb = (float*)smem;            // [2 kinds][4 wn][256 rows] = 8KB
    float as4[4], ad4[4];
#pragma unroll
    for (int j = 0; j < 4; ++j) {
      const int gn = n0 + wn * 64 + j * 16 + col;
      as4[j] = b2f(a_s[gn]);
      ad4[j] = b2f(a_d[gn]);
    }
#pragma unroll
    for (int i = 0; i < 8; ++i)
#pragma unroll
      for (int r = 0; r < 4; ++r) {
        float ps = 0.f, pd = 0.f;
#pragma unroll
        for (int j = 0; j < 4; ++j) { ps += acc[i][j][r] * as4[j]; pd += acc[i][j][r] * ad4[j]; }
#pragma unroll
        for (int off = 1; off < 16; off <<= 1) {  // reduce 16 col-lanes (same quad)
          ps += __shfl_xor(ps, off);
          pd += __shfl_xor(pd, off);
        }
        if (col == 0) {
          const int rr = wm * 128 + i * 16 + quad * 4 + r;   // 0..255
          alb[(0 * 4 + wn) * 256 + rr] = ps;
          alb[(1 * 4 + wn) * 256 + rr] = pd;
        }
      }
  }
  __syncthreads();
  {
    const float* alb = (const float*)smem;
    const int rr = tid >> 1, kind = tid & 1;
    float s = 0.f;
#pragma unroll
    for (int w = 0; w < 4; ++w) s += alb[(kind * 4 + w) * 256 + rr];
    float* dstp = kind ? al_d : al_s;
    dstp[(size_t)(m0 + rr) * 2 + nt] = s;   // exclusive owner: plain store
  }
  __syncthreads();

  // (2) C store via LDS staging, two 128-row halves (64KB each)
  // writer: pc = (wn*4+jj)^quad spreads 4 quads over 4 bank octets (free);
  // all acc indices compile-time constant (rule #20).
#pragma unroll
  for (int half = 0; half < 2; ++half) {
    if (wm == half) {
#pragma unroll
      for (int i = 0; i < 8; ++i)
#pragma unroll
        for (int jj = 0; jj < 4; ++jj)
#pragma unroll
          for (int r = 0; r < 4; ++r) {
            const int rl = i * 16 + quad * 4 + r;         // 0..127
            const int pc = (wn * 4 + jj) ^ quad;          // 0..15 chunks of 16 ushorts
            smem[rl * 256 + pc * 16 + col] = f2b(acc[i][jj][r]);
          }
    }
    __syncthreads();
#pragma unroll
    for (int s = 0; s < 8; ++s) {
      const int u = tid + 512 * s;
      const int rw = u >> 5, unit = u & 31;   // row 0..127, 16B-unit 0..31
      const int lc = unit >> 1, h16 = unit & 1;
      const int q = (rw >> 2) & 3;
      const ushort8 v = *(const ushort8*)&smem[rw * 256 + ((lc ^ q) * 16 + h16 * 8)];
      *(ushort8*)&C[(size_t)(m0 + half * 128 + rw) * Nn + n0 + unit * 8] = v;
    }
    __syncthreads();
  }
}

// ---------------- GAT aggregate: one wave per node, XCD-pinned audios ----------
// Edge-parallel scoring; per-edge w,s broadcast via __shfl. lrelu monotone =>
// max e_i = lrelu(max al_s_i + ald). Optional lg: fused temporal logits.
__global__ __launch_bounds__(256) void agg_k(const unsigned short* __restrict__ h,
                                             const float* __restrict__ al_s, const float* __restrict__ al_d,
                                             const int* __restrict__ row_ptr, const int* __restrict__ counts,
                                             const int* __restrict__ ssrc, const unsigned short* __restrict__ bias,
                                             unsigned short* __restrict__ out, int do_relu,
                                             void* __restrict__ out2, const int* __restrict__ flagp,
                                             const unsigned short* __restrict__ watt,
                                             float* __restrict__ lg) {
  const int wave = threadIdx.x >> 6, lane = threadIdx.x & 63;
  const int b = blockIdx.x;
  const int g = b & 7, r = b >> 3;          // g ~ XCD id (round-robin dispatch)
  const int a = g + 8 * (r / 200);          // audio pinned to XCD g
  const int chunk = r % 200;
  const int n = a * 800 + chunk * 4 + wave;
  const int head = lane >> 5;               // lanes 0-31: head0, 32-63: head1
  const int hl = lane & 31;
  const int hsel = lane & 32;
  const int deg = counts[n];
  const int base = row_ptr[n];
  const float ald = al_d[n * 2 + head];
  const float self_e = lrelu(al_s[n * 2 + head] + ald);

  float m = -1e30f;
  for (int i = hl; i < deg; i += 32) {
    const int s = ssrc[base + i];
    m = fmaxf(m, al_s[s * 2 + head]);
  }
#pragma unroll
  for (int off = 1; off < 32; off <<= 1) m = fmaxf(m, __shfl_xor(m, off));
  const float mx = fmaxf(lrelu(m + ald), self_e);

  const float w_self = __expf(self_e - mx);
  float acc[8];
  {
    const ushort8 hv = *(const ushort8*)&h[(unsigned)(n * 512 + lane * 8)];
#pragma unroll
    for (int j = 0; j < 8; ++j) acc[j] = w_self * b2f(hv[j]);
  }
  float dpart = 0.f;
  for (int t0 = 0; t0 < deg; t0 += 32) {
    const int cnt = min(32, deg - t0);
    int s = 0; float w = 0.f;
    if (hl < cnt) {
      s = ssrc[base + t0 + hl];
      w = __expf(lrelu(al_s[s * 2 + head] + ald) - mx);
      dpart += w;
    }
    for (int i = 0; i < cnt; ++i) {
      const float wb = __shfl(w, hsel + i);
      const int sb = __shfl(s, hsel + i);
      const ushort8 hv = *(const ushort8*)&h[(unsigned)(sb * 512 + lane * 8)];
#pragma unroll
      for (int j = 0; j < 8; ++j) acc[j] += wb * b2f(hv[j]);
    }
  }
#pragma unroll
  for (int off = 1; off < 32; off <<= 1) dpart += __shfl_xor(dpart, off);
  const float inv = 1.f / (w_self + dpart);

  const int c0 = hl * 8;
  ushort8 res;
  float ov[8];
#pragma unroll
  for (int j = 0; j < 8; ++j) {
    const float mine = acc[j] * inv;
    const float other = __shfl_xor(mine, 32);  // partner lane: other head, same cols
    float o = (mine + other) * 0.5f + b2f(bias[c0 + j]);
    if (do_relu) o = fmaxf(o, 0.f);
    ov[j] = o;
    res[j] = f2b(o);
  }
  if (lane < 32) {
    *(ushort8*)&out[(unsigned)(n * 256 + c0)] = res;
    if (out2) {
      if (*flagp) {
        float4* p = (float4*)((float*)out2 + (size_t)n * 256 + c0);
        p[0] = (float4){ov[0], ov[1], ov[2], ov[3]};
        p[1] = (float4){ov[4], ov[5], ov[6], ov[7]};
      } else {
        *(ushort8*)((unsigned short*)out2 + (size_t)n * 256 + c0) = res;
      }
    }
    if (lg) {  // fused temporal logits: dot(out_row, w_att) + b_att
      const ushort8 wv = *(const ushort8*)&watt[c0];
      float d = 0.f;
#pragma unroll
      for (int j = 0; j < 8; ++j) d += ov[j] * b2f(wv[j]);
#pragma unroll
      for (int off = 1; off < 32; off <<= 1) d += __shfl_xor(d, off);
      if (hl == 0) lg[n] = d + b2f(watt[256]);  // b_att sits right after w_att
    }
  }
}

// ---------------- temporal attention, grid-parallel ----------------
__global__ __launch_bounds__(256) void stats_k(const float* __restrict__ lg,
                                               float* __restrict__ mxv, float* __restrict__ invv) {
  __shared__ float red[256];
  const int a = blockIdx.x, t = threadIdx.x;
  float m = -1e30f;
  for (int i = t; i < 800; i += 256) m = fmaxf(m, lg[a * 800 + i]);
  red[t] = m; __syncthreads();
  for (int s = 128; s >= 1; s >>= 1) { if (t < s) red[t] = fmaxf(red[t], red[t + s]); __syncthreads(); }
  const float mx = red[0];
  __syncthreads();
  float sum = 0.f;
  for (int i = t; i < 800; i += 256) sum += __expf(lg[a * 800 + i] - mx);
  red[t] = sum; __syncthreads();
  for (int s = 128; s >= 1; s >>= 1) { if (t < s) red[t] += red[t + s]; __syncthreads(); }
  if (t == 0) { mxv[a] = mx; invv[a] = 1.f / red[0]; }
}

__global__ __launch_bounds__(256) void attended_k(const unsigned short* __restrict__ emb,
                                                  const float* __restrict__ lg,
                                                  const float* __restrict__ mxv,
                                                  const float* __restrict__ invv,
                                                  float* __restrict__ attended) {
  const int b = blockIdx.x;
  const int a = b >> 3, chunk = b & 7;
  const int t = threadIdx.x;
  __shared__ float ws[100];
  const int i0 = chunk * 100;
  const float mx = mxv[a], inv = invv[a];
  if (t < 100) ws[t] = __expf(lg[a * 800 + i0 + t] - mx) * inv;
  __syncthreads();
  float acc = 0.f;
  const unsigned short* base = emb + ((size_t)(a * 800 + i0)) * 256 + t;
#pragma unroll 4
  for (int j = 0; j < 100; ++j) acc += ws[j] * b2f(base[(size_t)j * 256]);
  atomicAdd(&attended[a * 256 + t], acc);
}

__global__ __launch_bounds__(256) void cls_k(const float* __restrict__ attended,
                                             const unsigned short* __restrict__ params,
                                             void* __restrict__ out, const int* __restrict__ flag) {
  __shared__ float red[256];
  const int a = blockIdx.x, t = threadIdx.x;
  const float v = attended[a * 256 + t];
  const float p0 = v * b2f(params[P_WCLS + t * 2]);
  const float p1 = v * b2f(params[P_WCLS + t * 2 + 1]);
  red[t] = p0; __syncthreads();
  for (int s = 128; s >= 1; s >>= 1) { if (t < s) red[t] += red[t + s]; __syncthreads(); }
  const float r0 = red[0];
  __syncthreads();
  red[t] = p1; __syncthreads();
  for (int s = 128; s >= 1; s >>= 1) { if (t < s) red[t] += red[t + s]; __syncthreads(); }
  const float r1 = red[0];
  if (t == 0) {
    const float o0 = r0 + b2f(params[P_BCLS]);
    const float o1 = r1 + b2f(params[P_BCLS + 1]);
    if (*flag) {
      ((float*)out)[(size_t)NN * 256 + a * 2]     = o0;
      ((float*)out)[(size_t)NN * 256 + a * 2 + 1] = o1;
    } else {
      ((unsigned short*)out)[(size_t)NN * 256 + a * 2]     = f2b(o0);
      ((unsigned short*)out)[(size_t)NN * 256 + a * 2 + 1] = f2b(o1);
    }
  }
}

extern "C" void kernel_launch(void* const* d_in, const int* in_sizes, int n_in,
                              void* d_out, int out_size, void* d_ws, size_t ws_size,
                              hipStream_t stream) {
  (void)in_sizes; (void)n_in; (void)out_size; (void)ws_size;
  const void* x_raw  = d_in[0];
  const int*  eidx   = (const int*)d_in[1];
  // d_in[2] = batch (unused: audio = n / 800)
  const int* src = eidx;
  const int* dst = eidx + EE;

  char* ws = (char*)d_ws;
  size_t off = 0;
  auto alloc = [&](size_t bytes) -> void* {
    void* p = ws + off;
    off += (bytes + 255) & ~(size_t)255;
    return p;
  };
  int* flag              = (int*)alloc(256);
  unsigned short* params = (unsigned short*)alloc(4096 * 2);
  unsigned short* W1T    = (unsigned short*)alloc((size_t)512 * 512 * 2);
  unsigned short* W2T    = (unsigned short*)alloc((size_t)512 * 256 * 2);
  unsigned short* scr    = (unsigned short*)alloc((size_t)NN * 512 * 2);  // hrel + emb16
  unsigned short* hbig   = (unsigned short*)alloc((size_t)NN * 512 * 2);
  // --- contiguous zero region (all sizes multiples of 256 B) ---
  int*   counts   = (int*)alloc((size_t)NN * 4);               // 204800
  int*   cursor   = (int*)alloc((size_t)NN * 4);               // 204800
  float* attended = (float*)alloc((size_t)NUM_AUDIOS * 256 * 4); // 65536
  float* al_s1    = (float*)alloc((size_t)NN * 2 * 4);         // 409600
  float* al_d1    = (float*)alloc((size_t)NN * 2 * 4);
  float* al_s2    = (float*)alloc((size_t)NN * 2 * 4);
  float* al_d2    = (float*)alloc((size_t)NN * 2 * 4);         // total 2113536 B = ZERO_F4*16
  // --- end zero region ---
  int*   rowp   = (int*)alloc((size_t)NN * 4);
  int*   ssrc   = (int*)alloc((size_t)EE * 4);
  float* lg     = (float*)alloc((size_t)NN * 4);
  float* mxv    = (float*)alloc(NUM_AUDIOS * 4);
  float* invv   = (float*)alloc(NUM_AUDIOS * 4);
  unsigned short* hrel  = scr;                         // layer-1 relu output [NN,256]
  unsigned short* emb16 = scr + (size_t)NN * 256;      // node_emb [NN,256] (bf16 copy)

  prolog0_k<<<dim3(ZERO_BLOCKS), 256, 0, stream>>>((float4*)counts,
                                                   (const unsigned short*)x_raw, flag);

  prep_k<<<dim3(PB_HIST), 256, 0, stream>>>(
      d_in[3], W1T, d_in[7], W2T,
      d_in[4], d_in[5], d_in[6], d_in[8], d_in[9],
      d_in[10], d_in[11], d_in[12], d_in[13], d_in[14],
      params, dst, counts, flag);

  rowptr_k<<<dim3(NUM_AUDIOS), 256, 0, stream>>>(counts, rowp);
  scatter_k<<<dim3(EE / 256), 256, 0, stream>>>(src, dst, rowp, cursor, ssrc);

  // Layer 1 (x conversion fused into GEMM staging; al fused into epilogue)
  gemm_bt<<<dim3(400), 512, 0, stream>>>(x_raw, W1T, hbig, 512, 512,
                                         params + P_AS1, params + P_AD1, al_s1, al_d1, flag);
  agg_k<<<dim3(NN / 4), 256, 0, stream>>>(hbig, al_s1, al_d1, rowp, counts, ssrc,
                                          params + P_B1, hrel, 1, nullptr, flag,
                                          params + P_WATT, nullptr);

  // Layer 2
  gemm_bt<<<dim3(400), 512, 0, stream>>>(hrel, W2T, hbig, 256, 512,
                                         params + P_AS2, params + P_AD2, al_s2, al_d2, nullptr);
  agg_k<<<dim3(NN / 4), 256, 0, stream>>>(hbig, al_s2, al_d2, rowp, counts, ssrc,
                                          params + P_B2, emb16, 0, d_out, flag,
                                          params + P_WATT, lg);

  // Temporal attention + classifier
  stats_k<<<dim3(NUM_AUDIOS), 256, 0, stream>>>(lg, mxv, invv);
  attended_k<<<dim3(NUM_AUDIOS * 8), 256, 0, stream>>>(emb16, lg, mxv, invv, attended);
  cls_k<<<dim3(NUM_AUDIOS), 256, 0, stream>>>(attended, params, d_out, flag);
}

// Round 5
// 422.765 us; speedup vs baseline: 2.0363x; 1.0091x over previous
//
#include <hip/hip_runtime.h>
#include <cstdint>
#include <cstddef>

// Problem constants (fixed by the reference).
#define NUM_AUDIOS 64
#define NODES_PER  800
#define NN         51200
#define EE         409600
// IN_C=512, HID=256, OUT=256, HEADS=2 -> both GAT linears output [N, 512] (2 heads x 256)

typedef __attribute__((ext_vector_type(8))) unsigned short ushort8;
typedef __attribute__((ext_vector_type(8))) __bf16 bf16x8;
typedef __attribute__((ext_vector_type(4))) float f32x4;

__device__ __forceinline__ float b2f(unsigned short h) {
  return __uint_as_float(((unsigned)h) << 16);
}
__device__ __forceinline__ unsigned short f2b(float f) {
  unsigned u = __float_as_uint(f);
  u += 0x7fffu + ((u >> 16) & 1u);  // RNE
  return (unsigned short)(u >> 16);
}
__device__ __forceinline__ float lrelu(float v) { return v > 0.f ? v : 0.2f * v; }

// Canonical bf16 parameter block offsets (u16 units)
#define P_AS1 0
#define P_AD1 512
#define P_B1  1024
#define P_AS2 1536
#define P_AD2 2048
#define P_B2  2560
#define P_WATT 3072
#define P_BATT 3328
#define P_WCLS 3336
#define P_BCLS 3848

// Zero region: counts|cursor|attended|al_s1|al_d1|al_s2|al_d2 (contiguous, 2113536 B)
#define ZERO_F4 132096   // float4 count
#define ZERO_BLOCKS 516  // 516*256 = 132096

// ---------------- prolog: zero atomic buffers + dtype probe ----------------
__global__ __launch_bounds__(256) void prolog0_k(float4* __restrict__ zbase,
                                                 const unsigned short* __restrict__ x,
                                                 int* __restrict__ flag) {
  const int i = blockIdx.x * 256 + threadIdx.x;
  if (i < ZERO_F4) zbase[i] = (float4){0.f, 0.f, 0.f, 0.f};
  if (blockIdx.x == 0) {
    __shared__ int s;
    if (threadIdx.x == 0) s = 0;
    __syncthreads();
    int big = 0;
    for (int k = threadIdx.x; k < 4096; k += 256) {
      const float v = b2f(x[k]);
      if (!(__builtin_fabsf(v) <= 1e4f)) big = 1;  // catches >1e4, inf, NaN
    }
    if (big) atomicOr(&s, 1);
    __syncthreads();
    if (threadIdx.x == 0) *flag = s;  // 1 = fp32 inputs, 0 = bf16 inputs
  }
}

// ---------------- union prep: params | transpose W1 | transpose W2 | hist ------
#define PB_PAR  10
#define PB_T1   (PB_PAR + 1024)
#define PB_T2   (PB_T1 + 512)
#define PB_HIST (PB_T2 + 1600)   // total grid = 3146

__global__ __launch_bounds__(256) void prep_k(
    const void* __restrict__ W1, unsigned short* __restrict__ W1T,
    const void* __restrict__ W2, unsigned short* __restrict__ W2T,
    const void* p0, const void* p1, const void* p2, const void* p3, const void* p4,
    const void* p5, const void* p6, const void* p7, const void* p8, const void* p9,
    unsigned short* __restrict__ params,
    const int* __restrict__ dst, int* __restrict__ counts,
    const int* __restrict__ flagp) {
  const int b = blockIdx.x, tid = threadIdx.x;
  const int f = *flagp;
  if (b < PB_PAR) {                        // small params -> canonical bf16 block
    const void* srcs[10] = {p0, p1, p2, p3, p4, p5, p6, p7, p8, p9};
    const int offs[10] = {P_AS1, P_AD1, P_B1, P_AS2, P_AD2, P_B2, P_WATT, P_BATT, P_WCLS, P_BCLS};
    const int lens[10] = {512, 512, 256, 512, 512, 256, 256, 1, 512, 2};
    const int s = b;
    for (int i = tid; i < lens[s]; i += 256)
      params[offs[s] + i] = f ? f2b(((const float*)srcs[s])[i])
                              : ((const unsigned short*)srcs[s])[i];
  } else if (b < PB_T1) {                  // W1 [512,512] -> W1T
    const int idx = (b - PB_PAR) * 256 + tid;
    const int n = idx >> 9, k = idx & 511;
    W1T[idx] = f ? f2b(((const float*)W1)[(size_t)k * 512 + n])
                 : ((const unsigned short*)W1)[(size_t)k * 512 + n];
  } else if (b < PB_T2) {                  // W2 [256,512] -> W2T
    const int idx = (b - PB_T1) * 256 + tid;
    const int n = idx >> 8, k = idx & 255;
    W2T[idx] = f ? f2b(((const float*)W2)[(size_t)k * 512 + n])
                 : ((const unsigned short*)W2)[(size_t)k * 512 + n];
  } else {                                 // histogram of dst
    const int e = (b - PB_T2) * 256 + tid;
    atomicAdd(&counts[dst[e]], 1);
  }
}

// ---------------- CSR build ----------------
__global__ __launch_bounds__(256) void rowptr_k(const int* __restrict__ counts, int* __restrict__ row_ptr) {
  __shared__ int sh[800];
  __shared__ int pre[200];
  const int a = blockIdx.x, t = threadIdx.x;
  for (int i = t; i < 800; i += 256) sh[i] = counts[a * 800 + i];
  __syncthreads();
  if (t < 200) pre[t] = sh[t * 4] + sh[t * 4 + 1] + sh[t * 4 + 2] + sh[t * 4 + 3];
  __syncthreads();
  if (t == 0) {
    int run = 0;
    for (int i = 0; i < 200; ++i) { const int v = pre[i]; pre[i] = run; run += v; }
  }
  __syncthreads();
  if (t < 200) {
    int b = a * 6400 + pre[t];
#pragma unroll
    for (int j = 0; j < 4; ++j) { row_ptr[a * 800 + t * 4 + j] = b; b += sh[t * 4 + j]; }
  }
}

__global__ __launch_bounds__(256) void scatter_k(const int* __restrict__ src, const int* __restrict__ dst,
                                                 const int* __restrict__ row_ptr, int* __restrict__ cursor,
                                                 int* __restrict__ ssrc) {
  const int e = blockIdx.x * 256 + threadIdx.x;
  const int d = dst[e];
  const int p = atomicAdd(&cursor[d], 1);
  ssrc[row_ptr[d] + p] = src[e];
}

// ---------------- 256x256 GEMM cores: 8 waves (2m x 4n), wave = 128x64 --------
// BK=32 reader (fp32 path): 4-chunk XOR swizzle, logical chunk q at physical
// q^(row&3).
__device__ __forceinline__ void mfma_tile256(const unsigned short* As, const unsigned short* Bs,
                                             int wm, int wn, int row, int quad, f32x4 acc[8][4]) {
  bf16x8 af[8], bq[4];
  const int pa = (quad ^ (row & 3)) * 8;  // physical k-chunk (bank swizzle)
#pragma unroll
  for (int i = 0; i < 8; ++i)
    af[i] = *(const bf16x8*)&As[(wm * 128 + i * 16 + row) * 32 + pa];
#pragma unroll
  for (int j = 0; j < 4; ++j)
    bq[j] = *(const bf16x8*)&Bs[(wn * 64 + j * 16 + row) * 32 + pa];
#pragma unroll
  for (int i = 0; i < 8; ++i)
#pragma unroll
    for (int j = 0; j < 4; ++j)
      acc[i][j] = __builtin_amdgcn_mfma_f32_16x16x32_bf16(af[i], bq[j], acc[i][j], 0, 0, 0);
}

// BK=64 reader (bf16 DMA path): 8-chunk XOR swizzle, logical chunk lc of row r
// at physical lc^(r&7). Row = 8 chunks of 16B (128B); banks: chunk*16B -> 8
// distinct 4-bank groups; 2 lanes/group same quad (2-way = free).
__device__ __forceinline__ void mfma_k64(const unsigned short* Ab, const unsigned short* Bb,
                                         int wm, int wn, int row, int quad, f32x4 acc[8][4]) {
#pragma unroll
  for (int kh = 0; kh < 2; ++kh) {
    bf16x8 af[8], bq[4];
#pragma unroll
    for (int i = 0; i < 8; ++i) {
      const int R = wm * 128 + i * 16 + row;
      const int p = (kh * 4 + quad) ^ (R & 7);
      af[i] = *(const bf16x8*)&Ab[(R * 8 + p) * 8];
    }
#pragma unroll
    for (int j = 0; j < 4; ++j) {
      const int R = wn * 64 + j * 16 + row;
      const int p = (kh * 4 + quad) ^ (R & 7);
      bq[j] = *(const bf16x8*)&Bb[(R * 8 + p) * 8];
    }
#pragma unroll
    for (int i = 0; i < 8; ++i)
#pragma unroll
      for (int j = 0; j < 4; ++j)
        acc[i][j] = __builtin_amdgcn_mfma_f32_16x16x32_bf16(af[i], bq[j], acc[i][j], 0, 0, 0);
  }
}

// ---------------- GEMM + fused attention-logit partials ----------------
// C[M,512] = A[M,K] @ B (BT[512,K]). 256x256 tile, 512 threads, 8 waves.
// n-tile = 256 cols = one head -> al_s/al_d via block-local LDS reduction,
// plain stores, NO atomics.
// bf16 path (GEMM2 + bf16 inputs): BK=64, 128KB dbuf, 8 loads in flight
// across each K-tile (counted vmcnt(8)), ONE barrier-pair + 64 MFMA per
// K-tile, setprio around the MFMA cluster (T3/T4/T5).
// fp32 path (GEMM1 when inputs fp32): UNCHANGED from round 4 (control arm).
// Epilogue: al LDS-reduce + C staged via LDS, coalesced 16B stores.
__global__ __launch_bounds__(512, 2) void gemm_bt(const void* __restrict__ Araw,
                                                  const unsigned short* __restrict__ BT,
                                                  unsigned short* __restrict__ C,
                                                  int K, int Nn,
                                                  const unsigned short* __restrict__ a_s,
                                                  const unsigned short* __restrict__ a_d,
                                                  float* __restrict__ al_s,
                                                  float* __restrict__ al_d,
                                                  const int* __restrict__ aflag) {
  __shared__ unsigned short smem[65536];   // 128KB; epilogue reuses low 64KB
  const int tid = threadIdx.x;
  const int wave = tid >> 6, lane = tid & 63;
  const int bid = blockIdx.x;
  const int g = bid & 7, bt = bid >> 3;              // 8 XCDs x 50 blocks
  const int mt = bt >> 1, nt = bt & 1;               // 25 m-tiles/XCD, nt innermost
  const int m0 = (g * 25 + mt) * 256;
  const int n0 = nt * 256;                           // head = nt
  const int wm = wave >> 2, wn = wave & 3;
  const int row = lane & 15, quad = lane >> 4;
  const int col = lane & 15;
  f32x4 acc[8][4];
#pragma unroll
  for (int i = 0; i < 8; ++i)
#pragma unroll
    for (int j = 0; j < 4; ++j) acc[i][j] = (f32x4){0.f, 0.f, 0.f, 0.f};

  const bool a_is_f32 = (aflag != nullptr) && (*aflag != 0);
  const unsigned short* A16 = (const unsigned short*)Araw;
  const float* A32 = (const float*)Araw;

  if (!a_is_f32) {
    // ---- BK=64 pipeline: buffer b at smem + b*32768 (A 32KB | B 32KB) ----
    const int nk = K >> 6;
    auto stage64 = [&](int buf, int k0) {
      unsigned short* Ab = smem + buf * 32768;
      unsigned short* Bb = Ab + 16384;
#pragma unroll
      for (int ld = 0; ld < 4; ++ld) {
        const int cc = ld * 512 + tid;
        const int rw = cc >> 3, ch = cc & 7;         // row 0..255, chunk 0..7
        const int kc = ((ch ^ (rw & 7)) * 8);        // inverse-swizzled source
        __builtin_amdgcn_global_load_lds(
            (const __attribute__((address_space(1))) void*)(A16 + (size_t)(m0 + rw) * K + k0 + kc),
            (__attribute__((address_space(3))) void*)(Ab + (size_t)cc * 8),
            16, 0, 0);
        __builtin_amdgcn_global_load_lds(
            (const __attribute__((address_space(1))) void*)(BT + (size_t)(n0 + rw) * K + k0 + kc),
            (__attribute__((address_space(3))) void*)(Bb + (size_t)cc * 8),
            16, 0, 0);
      }
    };
    stage64(0, 0);                        // prologue: K-tile 0 in flight (8 loads)
    for (int t = 0; t < nk; ++t) {
      if (t + 1 < nk) {
        stage64((t + 1) & 1, (t + 1) << 6);          // +8 newer loads
        asm volatile("s_waitcnt vmcnt(8)" ::: "memory");  // tile t landed
      } else {
        asm volatile("s_waitcnt vmcnt(0)" ::: "memory");
      }
      __builtin_amdgcn_sched_barrier(0);
      __builtin_amdgcn_s_barrier();       // all waves: tile t ready
      __builtin_amdgcn_sched_barrier(0);
      __builtin_amdgcn_s_setprio(1);
      mfma_k64(smem + (t & 1) * 32768, smem + (t & 1) * 32768 + 16384,
               wm, wn, row, quad, acc);
      __builtin_amdgcn_s_setprio(0);
      __builtin_amdgcn_sched_barrier(0);
      __builtin_amdgcn_s_barrier();       // readers done -> buffer reusable
    }
  } else {
    // ---- fp32 path: UNCHANGED round-4 structure (control) ----
    unsigned short* As = smem;            // single-buffered, BK=32
    unsigned short* Bs = smem + 8192;
    const int srow0 = tid >> 2;
    const int kph = tid & 3;
    for (int k0 = 0; k0 < K; k0 += 32) {
      ushort8 pk[2];
#pragma unroll
      for (int p = 0; p < 2; ++p) {
        const int arow = p * 128 + srow0;
        const int kc = ((kph ^ (arow & 3)) * 8);
        const float* ap = A32 + (size_t)(m0 + arow) * K + k0 + kc;
        const float4 f0 = *(const float4*)ap;
        const float4 f1 = *(const float4*)(ap + 4);
        pk[p][0] = f2b(f0.x); pk[p][1] = f2b(f0.y); pk[p][2] = f2b(f0.z); pk[p][3] = f2b(f0.w);
        pk[p][4] = f2b(f1.x); pk[p][5] = f2b(f1.y); pk[p][6] = f2b(f1.z); pk[p][7] = f2b(f1.w);
      }
      __syncthreads();  // previous iteration's LDS readers done
#pragma unroll
      for (int p = 0; p < 2; ++p) {
        const int arow = p * 128 + srow0;
        const int kc = ((kph ^ (arow & 3)) * 8);
        __builtin_amdgcn_global_load_lds(
            (const __attribute__((address_space(1))) void*)(BT + (size_t)(n0 + arow) * K + k0 + kc),
            (__attribute__((address_space(3))) void*)(Bs + (size_t)(p * 512 + tid) * 8),
            16, 0, 0);
        *(ushort8*)&As[(size_t)(p * 512 + tid) * 8] = pk[p];
      }
      __syncthreads();  // ds_writes visible + B DMA drained (vmcnt0 before barrier)
      mfma_tile256(As, Bs, wm, wn, row, quad, acc);
    }
  }

  // ---------------- epilogue ----------------
  __syncthreads();  // all K-loop LDS readers done before smem reuse

  // (1) al partials -> LDS -> plain global stores (block owns m-rows x head nt)
  {
    float* alb = (float*)smem;            // [2 kinds][4 wn][256 rows] = 8KB
    float as4[4], ad4[4];
#pragma unroll
    for (int j = 0; j < 4; ++j) {
      const int gn = n0 + wn * 64 + j * 16 + col;
      as4[j] = b2f(a_s[gn]);
      ad4[j] = b2f(a_d[gn]);
    }
#pragma unroll
    for (int i = 0; i < 8; ++i)
#pragma unroll
      for (int r = 0; r < 4; ++r) {
        float ps = 0.f, pd = 0.f;
#pragma unroll
        for (int j = 0; j < 4; ++j) { ps += acc[i][j][r] * as4[j]; pd += acc[i][j][r] * ad4[j]; }
#pragma unroll
        for (int off = 1; off < 16; off <<= 1) {  // reduce 16 col-lanes (same quad)
          ps += __shfl_xor(ps, off);
          pd += __shfl_xor(pd, off);
        }
        if (col == 0) {
          const int rr = wm * 128 + i * 16 + quad * 4 + r;   // 0..255
          alb[(0 * 4 + wn) * 256 + rr] = ps;
          alb[(1 * 4 + wn) * 256 + rr] = pd;
        }
      }
  }
  __syncthreads();
  {
    const float* alb = (const float*)smem;
    const int rr = tid >> 1, kind = tid & 1;
    float s = 0.f;
#pragma unroll
    for (int w = 0; w < 4; ++w) s += alb[(kind * 4 + w) * 256 + rr];
    float* dstp = kind ? al_d : al_s;
    dstp[(size_t)(m0 + rr) * 2 + nt] = s;   // exclusive owner: plain store
  }
  __syncthreads();

  // (2) C store via LDS staging, two 128-row halves
  // writer: pc = (wn*4+jj)^quad spreads 4 quads over 4 bank octets (free);
  // all acc indices compile-time constant (rule #20).
#pragma unroll
  for (int half = 0; half < 2; ++half) {
    if (wm == half) {
#pragma unroll
      for (int i = 0; i < 8; ++i)
#pragma unroll
        for (int jj = 0; jj < 4; ++jj)
#pragma unroll
          for (int r = 0; r < 4; ++r) {
            const int rl = i * 16 + quad * 4 + r;         // 0..127
            const int pc = (wn * 4 + jj) ^ quad;          // 0..15 chunks of 16 ushorts
            smem[rl * 256 + pc * 16 + col] = f2b(acc[i][jj][r]);
          }
    }
    __syncthreads();
#pragma unroll
    for (int s = 0; s < 8; ++s) {
      const int u = tid + 512 * s;
      const int rw = u >> 5, unit = u & 31;   // row 0..127, 16B-unit 0..31
      const int lc = unit >> 1, h16 = unit & 1;
      const int q = (rw >> 2) & 3;
      const ushort8 v = *(const ushort8*)&smem[rw * 256 + ((lc ^ q) * 16 + h16 * 8)];
      *(ushort8*)&C[(size_t)(m0 + half * 128 + rw) * Nn + n0 + unit * 8] = v;
    }
    __syncthreads();
  }
}

// ---------------- GAT aggregate: one wave per node, XCD-pinned audios ----------
// Edge-parallel scoring; per-edge w,s broadcast via __shfl. lrelu monotone =>
// max e_i = lrelu(max al_s_i + ald). Optional lg: fused temporal logits.
__global__ __launch_bounds__(256) void agg_k(const unsigned short* __restrict__ h,
                                             const float* __restrict__ al_s, const float* __restrict__ al_d,
                                             const int* __restrict__ row_ptr, const int* __restrict__ counts,
                                             const int* __restrict__ ssrc, const unsigned short* __restrict__ bias,
                                             unsigned short* __restrict__ out, int do_relu,
                                             void* __restrict__ out2, const int* __restrict__ flagp,
                                             const unsigned short* __restrict__ watt,
                                             float* __restrict__ lg) {
  const int wave = threadIdx.x >> 6, lane = threadIdx.x & 63;
  const int b = blockIdx.x;
  const int g = b & 7, r = b >> 3;          // g ~ XCD id (round-robin dispatch)
  const int a = g + 8 * (r / 200);          // audio pinned to XCD g
  const int chunk = r % 200;
  const int n = a * 800 + chunk * 4 + wave;
  const int head = lane >> 5;               // lanes 0-31: head0, 32-63: head1
  const int hl = lane & 31;
  const int hsel = lane & 32;
  const int deg = counts[n];
  const int base = row_ptr[n];
  const float ald = al_d[n * 2 + head];
  const float self_e = lrelu(al_s[n * 2 + head] + ald);

  float m = -1e30f;
  for (int i = hl; i < deg; i += 32) {
    const int s = ssrc[base + i];
    m = fmaxf(m, al_s[s * 2 + head]);
  }
#pragma unroll
  for (int off = 1; off < 32; off <<= 1) m = fmaxf(m, __shfl_xor(m, off));
  const float mx = fmaxf(lrelu(m + ald), self_e);

  const float w_self = __expf(self_e - mx);
  float acc[8];
  {
    const ushort8 hv = *(const ushort8*)&h[(unsigned)(n * 512 + lane * 8)];
#pragma unroll
    for (int j = 0; j < 8; ++j) acc[j] = w_self * b2f(hv[j]);
  }
  float dpart = 0.f;
  for (int t0 = 0; t0 < deg; t0 += 32) {
    const int cnt = min(32, deg - t0);
    int s = 0; float w = 0.f;
    if (hl < cnt) {
      s = ssrc[base + t0 + hl];
      w = __expf(lrelu(al_s[s * 2 + head] + ald) - mx);
      dpart += w;
    }
    for (int i = 0; i < cnt; ++i) {
      const float wb = __shfl(w, hsel + i);
      const int sb = __shfl(s, hsel + i);
      const ushort8 hv = *(const ushort8*)&h[(unsigned)(sb * 512 + lane * 8)];
#pragma unroll
      for (int j = 0; j < 8; ++j) acc[j] += wb * b2f(hv[j]);
    }
  }
#pragma unroll
  for (int off = 1; off < 32; off <<= 1) dpart += __shfl_xor(dpart, off);
  const float inv = 1.f / (w_self + dpart);

  const int c0 = hl * 8;
  ushort8 res;
  float ov[8];
#pragma unroll
  for (int j = 0; j < 8; ++j) {
    const float mine = acc[j] * inv;
    const float other = __shfl_xor(mine, 32);  // partner lane: other head, same cols
    float o = (mine + other) * 0.5f + b2f(bias[c0 + j]);
    if (do_relu) o = fmaxf(o, 0.f);
    ov[j] = o;
    res[j] = f2b(o);
  }
  if (lane < 32) {
    *(ushort8*)&out[(unsigned)(n * 256 + c0)] = res;
    if (out2) {
      if (*flagp) {
        float4* p = (float4*)((float*)out2 + (size_t)n * 256 + c0);
        p[0] = (float4){ov[0], ov[1], ov[2], ov[3]};
        p[1] = (float4){ov[4], ov[5], ov[6], ov[7]};
      } else {
        *(ushort8*)((unsigned short*)out2 + (size_t)n * 256 + c0) = res;
      }
    }
    if (lg) {  // fused temporal logits: dot(out_row, w_att) + b_att
      const ushort8 wv = *(const ushort8*)&watt[c0];
      float d = 0.f;
#pragma unroll
      for (int j = 0; j < 8; ++j) d += ov[j] * b2f(wv[j]);
#pragma unroll
      for (int off = 1; off < 32; off <<= 1) d += __shfl_xor(d, off);
      if (hl == 0) lg[n] = d + b2f(watt[256]);  // b_att sits right after w_att
    }
  }
}

// ---------------- temporal attention, grid-parallel ----------------
__global__ __launch_bounds__(256) void stats_k(const float* __restrict__ lg,
                                               float* __restrict__ mxv, float* __restrict__ invv) {
  __shared__ float red[256];
  const int a = blockIdx.x, t = threadIdx.x;
  float m = -1e30f;
  for (int i = t; i < 800; i += 256) m = fmaxf(m, lg[a * 800 + i]);
  red[t] = m; __syncthreads();
  for (int s = 128; s >= 1; s >>= 1) { if (t < s) red[t] = fmaxf(red[t], red[t + s]); __syncthreads(); }
  const float mx = red[0];
  __syncthreads();
  float sum = 0.f;
  for (int i = t; i < 800; i += 256) sum += __expf(lg[a * 800 + i] - mx);
  red[t] = sum; __syncthreads();
  for (int s = 128; s >= 1; s >>= 1) { if (t < s) red[t] += red[t + s]; __syncthreads(); }
  if (t == 0) { mxv[a] = mx; invv[a] = 1.f / red[0]; }
}

__global__ __launch_bounds__(256) void attended_k(const unsigned short* __restrict__ emb,
                                                  const float* __restrict__ lg,
                                                  const float* __restrict__ mxv,
                                                  const float* __restrict__ invv,
                                                  float* __restrict__ attended) {
  const int b = blockIdx.x;
  const int a = b >> 3, chunk = b & 7;
  const int t = threadIdx.x;
  __shared__ float ws[100];
  const int i0 = chunk * 100;
  const float mx = mxv[a], inv = invv[a];
  if (t < 100) ws[t] = __expf(lg[a * 800 + i0 + t] - mx) * inv;
  __syncthreads();
  float acc = 0.f;
  const unsigned short* base = emb + ((size_t)(a * 800 + i0)) * 256 + t;
#pragma unroll 4
  for (int j = 0; j < 100; ++j) acc += ws[j] * b2f(base[(size_t)j * 256]);
  atomicAdd(&attended[a * 256 + t], acc);
}

__global__ __launch_bounds__(256) void cls_k(const float* __restrict__ attended,
                                             const unsigned short* __restrict__ params,
                                             void* __restrict__ out, const int* __restrict__ flag) {
  __shared__ float red[256];
  const int a = blockIdx.x, t = threadIdx.x;
  const float v = attended[a * 256 + t];
  const float p0 = v * b2f(params[P_WCLS + t * 2]);
  const float p1 = v * b2f(params[P_WCLS + t * 2 + 1]);
  red[t] = p0; __syncthreads();
  for (int s = 128; s >= 1; s >>= 1) { if (t < s) red[t] += red[t + s]; __syncthreads(); }
  const float r0 = red[0];
  __syncthreads();
  red[t] = p1; __syncthreads();
  for (int s = 128; s >= 1; s >>= 1) { if (t < s) red[t] += red[t + s]; __syncthreads(); }
  const float r1 = red[0];
  if (t == 0) {
    const float o0 = r0 + b2f(params[P_BCLS]);
    const float o1 = r1 + b2f(params[P_BCLS + 1]);
    if (*flag) {
      ((float*)out)[(size_t)NN * 256 + a * 2]     = o0;
      ((float*)out)[(size_t)NN * 256 + a * 2 + 1] = o1;
    } else {
      ((unsigned short*)out)[(size_t)NN * 256 + a * 2]     = f2b(o0);
      ((unsigned short*)out)[(size_t)NN * 256 + a * 2 + 1] = f2b(o1);
    }
  }
}

extern "C" void kernel_launch(void* const* d_in, const int* in_sizes, int n_in,
                              void* d_out, int out_size, void* d_ws, size_t ws_size,
                              hipStream_t stream) {
  (void)in_sizes; (void)n_in; (void)out_size; (void)ws_size;
  const void* x_raw  = d_in[0];
  const int*  eidx   = (const int*)d_in[1];
  // d_in[2] = batch (unused: audio = n / 800)
  const int* src = eidx;
  const int* dst = eidx + EE;

  char* ws = (char*)d_ws;
  size_t off = 0;
  auto alloc = [&](size_t bytes) -> void* {
    void* p = ws + off;
    off += (bytes + 255) & ~(size_t)255;
    return p;
  };
  int* flag              = (int*)alloc(256);
  unsigned short* params = (unsigned short*)alloc(4096 * 2);
  unsigned short* W1T    = (unsigned short*)alloc((size_t)512 * 512 * 2);
  unsigned short* W2T    = (unsigned short*)alloc((size_t)512 * 256 * 2);
  unsigned short* scr    = (unsigned short*)alloc((size_t)NN * 512 * 2);  // hrel + emb16
  unsigned short* hbig   = (unsigned short*)alloc((size_t)NN * 512 * 2);
  // --- contiguous zero region (all sizes multiples of 256 B) ---
  int*   counts   = (int*)alloc((size_t)NN * 4);               // 204800
  int*   cursor   = (int*)alloc((size_t)NN * 4);               // 204800
  float* attended = (float*)alloc((size_t)NUM_AUDIOS * 256 * 4); // 65536
  float* al_s1    = (float*)alloc((size_t)NN * 2 * 4);         // 409600
  float* al_d1    = (float*)alloc((size_t)NN * 2 * 4);
  float* al_s2    = (float*)alloc((size_t)NN * 2 * 4);
  float* al_d2    = (float*)alloc((size_t)NN * 2 * 4);         // total 2113536 B = ZERO_F4*16
  // --- end zero region ---
  int*   rowp   = (int*)alloc((size_t)NN * 4);
  int*   ssrc   = (int*)alloc((size_t)EE * 4);
  float* lg     = (float*)alloc((size_t)NN * 4);
  float* mxv    = (float*)alloc(NUM_AUDIOS * 4);
  float* invv   = (float*)alloc(NUM_AUDIOS * 4);
  unsigned short* hrel  = scr;                         // layer-1 relu output [NN,256]
  unsigned short* emb16 = scr + (size_t)NN * 256;      // node_emb [NN,256] (bf16 copy)

  prolog0_k<<<dim3(ZERO_BLOCKS), 256, 0, stream>>>((float4*)counts,
                                                   (const unsigned short*)x_raw, flag);

  prep_k<<<dim3(PB_HIST), 256, 0, stream>>>(
      d_in[3], W1T, d_in[7], W2T,
      d_in[4], d_in[5], d_in[6], d_in[8], d_in[9],
      d_in[10], d_in[11], d_in[12], d_in[13], d_in[14],
      params, dst, counts, flag);

  rowptr_k<<<dim3(NUM_AUDIOS), 256, 0, stream>>>(counts, rowp);
  scatter_k<<<dim3(EE / 256), 256, 0, stream>>>(src, dst, rowp, cursor, ssrc);

  // Layer 1 (x conversion fused into GEMM staging; al fused into epilogue)
  gemm_bt<<<dim3(400), 512, 0, stream>>>(x_raw, W1T, hbig, 512, 512,
                                         params + P_AS1, params + P_AD1, al_s1, al_d1, flag);
  agg_k<<<dim3(NN / 4), 256, 0, stream>>>(hbig, al_s1, al_d1, rowp, counts, ssrc,
                                          params + P_B1, hrel, 1, nullptr, flag,
                                          params + P_WATT, nullptr);

  // Layer 2
  gemm_bt<<<dim3(400), 512, 0, stream>>>(hrel, W2T, hbig, 256, 512,
                                         params + P_AS2, params + P_AD2, al_s2, al_d2, nullptr);
  agg_k<<<dim3(NN / 4), 256, 0, stream>>>(hbig, al_s2, al_d2, rowp, counts, ssrc,
                                          params + P_B2, emb16, 0, d_out, flag,
                                          params + P_WATT, lg);

  // Temporal attention + classifier
  stats_k<<<dim3(NUM_AUDIOS), 256, 0, stream>>>(lg, mxv, invv);
  attended_k<<<dim3(NUM_AUDIOS * 8), 256, 0, stream>>>(emb16, lg, mxv, invv, attended);
  cls_k<<<dim3(NUM_AUDIOS), 256, 0, stream>>>(attended, params, d_out, flag);
}